// Round 1
// baseline (1427.704 us; speedup 1.0000x reference)
//
#include <hip/hip_runtime.h>

#define B   128
#define Nv  256
#define Mn  12
#define Ev  256
#define Hd  128
#define Dd  3
#define Kk  2
#define AFd 82
#define BFd 6
#define BN  (B*Nv)   // 32768
#define BE  (B*Ev)   // 32768

static constexpr int TR = 32;

enum { EPI_NONE = 0, EPI_LRELU = 1, EPI_TANHDOT = 2, EPI_ZMAIN = 3 };

__device__ __forceinline__ float lrelu(float x) { return x > 0.f ? x : 0.1f * x; }
__device__ __forceinline__ float sigmoidf(float x) { return 1.f / (1.f + expf(-x)); }

// Generic tiled GEMM: out(R x 128) = epi( [A1|A2](R x (K1+K2)) @ [W1;W2] + bias )
// - rowidx: optional row indirection for A1 (gather GEMM); only used when A2==null
// - W2==null means W1 spans all K rows
// - blockIdx.y selects a weight/bias/out slice via *strideY (used for the K=2 attention GEMM)
template<int EPI>
__global__ __launch_bounds__(256) void gemm128(
    const float* __restrict__ A1, int lda1, int K1,
    const float* __restrict__ A2, int lda2, int K2,
    const int* __restrict__ rowidx,
    const float* __restrict__ W1, int ldw1,
    const float* __restrict__ W2, int ldw2,
    long wstrideY,
    const float* __restrict__ b1, long b1sY,
    const float* __restrict__ b2,
    float* __restrict__ out, long ostrideY,
    const float* __restrict__ e0,
    const float* __restrict__ e1, long e1sY,
    const float* __restrict__ e2)
{
    const int Ktot = K1 + K2;
    const int row0 = blockIdx.x * TR;
    const int ky   = blockIdx.y;
    const int t    = threadIdx.x;

    const float* W1y = W1 + (long)ky * wstrideY;

    __shared__ float As[TR][TR + 4];     // [k][row] (transposed)
    __shared__ float Ws[TR][128 + 4];    // [k][col]

    float acc[4][4] = {};

    const int rg  = t >> 5;              // 0..7  (row group of 4)
    const int cg  = t & 31;              // 0..31 (col group of 4)
    const int lr  = t >> 3;              // 0..31 (load row)
    const int lk4 = (t & 7) << 2;        // 0,4,...,28 (load k base)

    const int  grow = row0 + lr;
    const long arow = rowidx ? (long)rowidx[grow] : (long)grow;

    const int nkt = (Ktot + TR - 1) / TR;
    for (int kt = 0; kt < nkt; ++kt) {
        // ---- load A tile (transposed into LDS) ----
        {
            const int kbase = kt * TR + lk4;
            float v[4];
            #pragma unroll
            for (int j = 0; j < 4; ++j) {
                const int kg = kbase + j;
                float x = 0.f;
                if (kg < K1)            x = A1[arow * lda1 + kg];
                else if (kg < Ktot)     x = A2[(long)grow * lda2 + (kg - K1)];
                v[j] = x;
            }
            #pragma unroll
            for (int j = 0; j < 4; ++j) As[lk4 + j][lr] = v[j];
        }
        // ---- load W tile ----
        {
            const int c4 = (t & 31) << 2;
            #pragma unroll
            for (int p = 0; p < 4; ++p) {
                const int kk = (t >> 5) + p * 8;
                const int kg = kt * TR + kk;
                float4 w = make_float4(0.f, 0.f, 0.f, 0.f);
                if (kg < Ktot) {
                    if (W2 && kg >= K1) w = *(const float4*)&W2[(long)(kg - K1) * ldw2 + c4];
                    else                w = *(const float4*)&W1y[(long)kg * ldw1 + c4];
                }
                *(float4*)&Ws[kk][c4] = w;
            }
        }
        __syncthreads();
        #pragma unroll
        for (int kk = 0; kk < TR; ++kk) {
            const float4 av = *(const float4*)&As[kk][rg << 2];
            const float4 wv = *(const float4*)&Ws[kk][cg << 2];
            const float aa[4] = {av.x, av.y, av.z, av.w};
            const float ww[4] = {wv.x, wv.y, wv.z, wv.w};
            #pragma unroll
            for (int i = 0; i < 4; ++i)
                #pragma unroll
                for (int j = 0; j < 4; ++j)
                    acc[i][j] = fmaf(aa[i], ww[j], acc[i][j]);
        }
        __syncthreads();
    }

    // ---- epilogue ----
    if constexpr (EPI == EPI_TANHDOT) {
        // a[b,k,n] = sum_g tanh(acc+bias)*sf[b,g]*wbmm[k,g] + wbmm_b[k]
        __shared__ float Us[128];
        __shared__ float red[TR][33];
        const int b = row0 >> 8;   // N=256 rows per batch, tiles never cross b
        if (t < 128) Us[t] = e0[b * Hd + t] * e1[(long)ky * e1sY + t];
        __syncthreads();
        const float* bb = b1 + (long)ky * b1sY;
        #pragma unroll
        for (int i = 0; i < 4; ++i) {
            float s = 0.f;
            #pragma unroll
            for (int j = 0; j < 4; ++j) {
                const int c = (cg << 2) + j;
                s += tanhf(acc[i][j] + bb[c]) * Us[c];
            }
            red[(rg << 2) + i][cg] = s;
        }
        __syncthreads();
        if (t < TR) {
            float s = 0.f;
            #pragma unroll
            for (int q = 0; q < 32; ++q) s += red[t][q];
            const int gr = row0 + t;
            out[(long)(gr >> 8) * (Kk * Nv) + (gr & 255) + (long)ky * ostrideY] = s + e2[ky];
        }
    } else if constexpr (EPI == EPI_ZMAIN) {
        // z = sig(acc + b1 + c_zm2[b]);  out = (1-z)*main_self + z*s2m[b]
        const int b = row0 >> 8;
        #pragma unroll
        for (int i = 0; i < 4; ++i) {
            const int row = row0 + (rg << 2) + i;
            #pragma unroll
            for (int j = 0; j < 4; ++j) {
                const int c = (cg << 2) + j;
                const float z = sigmoidf(acc[i][j] + b1[c] + e0[b * Hd + c]);
                const float msv = e1[(long)row * Hd + c];
                out[(long)row * Hd + c] = (1.f - z) * msv + z * e2[b * Hd + c];
            }
        }
    } else {
        #pragma unroll
        for (int i = 0; i < 4; ++i) {
            const int row = row0 + (rg << 2) + i;
            #pragma unroll
            for (int j = 0; j < 4; ++j) {
                const int c = (cg << 2) + j;
                float y = acc[i][j];
                if (b1) y += b1[c];
                if (b2) y += b2[c];
                if constexpr (EPI == EPI_LRELU) y = lrelu(y);
                out[(long)row * Hd + c] = y;
            }
        }
    }
}

// sf[b,h] = sum_n vf[b,n,h]*vmask[b,n]
__global__ __launch_bounds__(256) void k_sf(const float* __restrict__ vf,
                                            const float* __restrict__ vmask,
                                            float* __restrict__ sf)
{
    const int b = blockIdx.x, t = threadIdx.x;
    const int h = t & 127, half = t >> 7;
    float acc = 0.f;
    for (int n = half * 128; n < half * 128 + 128; ++n)
        acc += vf[((long)b * Nv + n) * Hd + h] * vmask[b * Nv + n];
    __shared__ float red[2][Hd];
    red[half][h] = acc;
    __syncthreads();
    if (t < Hd) sf[b * Hd + t] = red[0][t] + red[1][t];
}

// masked softmax over n (N=256) per (b,k); also s_attn = sum(attn)
__global__ __launch_bounds__(256) void k_softmax(const float* __restrict__ a,
                                                 const float* __restrict__ vmask,
                                                 float* __restrict__ attn,
                                                 float* __restrict__ s_attn)
{
    const int bk = blockIdx.x, b = bk >> 1, t = threadIdx.x;
    const int wid = t >> 6, lane = t & 63;
    const float v = a[bk * Nv + t];
    float m = v;
    #pragma unroll
    for (int o = 1; o < 64; o <<= 1) m = fmaxf(m, __shfl_xor(m, o));
    __shared__ float lmax[4];
    if (lane == 0) lmax[wid] = m;
    __syncthreads();
    m = fmaxf(fmaxf(lmax[0], lmax[1]), fmaxf(lmax[2], lmax[3]));
    const float e = expf(v - m) * vmask[b * Nv + t];
    float s = e;
    #pragma unroll
    for (int o = 1; o < 64; o <<= 1) s += __shfl_xor(s, o);
    __shared__ float lsum[4];
    if (lane == 0) lsum[wid] = s;
    __syncthreads();
    s = lsum[0] + lsum[1] + lsum[2] + lsum[3];
    const float denom = s + 1e-6f;
    attn[bk * Nv + t] = e / denom;
    if (t == 0) s_attn[bk] = s / denom;
}

// t[b,k,h] = sum_n attn[b,k,n]*vf[b,n,h]
__global__ __launch_bounds__(256) void k_t(const float* __restrict__ attn,
                                           const float* __restrict__ vf,
                                           float* __restrict__ tb)
{
    const int bk = blockIdx.x, b = bk >> 1, t = threadIdx.x;
    __shared__ float at[Nv];
    at[t] = attn[bk * Nv + t];
    __syncthreads();
    const int h = t & 127, half = t >> 7;
    float acc = 0.f;
    for (int n = half * 128; n < half * 128 + 128; ++n)
        acc += at[n] * vf[((long)b * Nv + n) * Hd + h];
    __shared__ float red[2][Hd];
    red[half][h] = acc;
    __syncthreads();
    if (t < Hd) tb[bk * Hd + t] = red[0][t] + red[1][t];
}

// m_vec[b,k,g] = sum_h t[b,k,h]*Wm[k,h,g] + s_attn[b,k]*bm[k,g]
__global__ __launch_bounds__(128) void k_mvec(const float* __restrict__ tb,
                                              const float* __restrict__ s_attn,
                                              const float* __restrict__ Wm,
                                              const float* __restrict__ bm,
                                              float* __restrict__ m_vec)
{
    const int bk = blockIdx.x, g = threadIdx.x, k = bk & 1;
    __shared__ float ts[Hd];
    ts[g] = tb[bk * Hd + g];
    __syncthreads();
    const float* W = Wm + (long)k * Hd * Hd;
    float acc = 0.f;
    for (int h = 0; h < Hd; ++h) acc += ts[h] * W[h * Hd + g];
    m_vec[bk * Hd + g] = acc + s_attn[bk] * bm[k * Hd + g];
}

// m2s[b,g] = tanh(sum_j m_vec[b,j]*W[j,g] + b[g]),  j over 256
__global__ __launch_bounds__(128) void k_m2s(const float* __restrict__ m_vec,
                                             const float* __restrict__ W,
                                             const float* __restrict__ bb,
                                             float* __restrict__ m2s)
{
    const int b = blockIdx.x, g = threadIdx.x;
    __shared__ float ms[2 * Hd];
    ms[g] = m_vec[b * 2 * Hd + g];
    ms[g + Hd] = m_vec[b * 2 * Hd + Hd + g];
    __syncthreads();
    float acc = 0.f;
    for (int j = 0; j < 2 * Hd; ++j) acc += ms[j] * W[j * Hd + g];
    m2s[b * Hd + g] = tanhf(acc + bb[g]);
}

// nei_label[bn,h] = sum_m mask*lrelu(P[atom_adj]+Q[bond_adj])
__global__ __launch_bounds__(128) void k_gather(const float* __restrict__ P,
                                                const float* __restrict__ Q,
                                                const int* __restrict__ aadj,
                                                const int* __restrict__ badj,
                                                const float* __restrict__ nmask,
                                                float* __restrict__ nei)
{
    const int bn = blockIdx.x, h = threadIdx.x;
    __shared__ int ai[Mn];
    __shared__ int bi[Mn];
    __shared__ float mk[Mn];
    if (h < Mn) {
        ai[h] = aadj[(long)bn * Mn + h];
        bi[h] = badj[(long)bn * Mn + h];
        mk[h] = nmask[(long)bn * Mn + h];
    }
    __syncthreads();
    float acc = 0.f;
    #pragma unroll
    for (int m = 0; m < Mn; ++m) {
        const float v = P[(long)ai[m] * Hd + h] + Q[(long)bi[m] * Hd + h];
        acc += mk[m] * lrelu(v);
    }
    nei[(long)bn * Hd + h] = acc;
}

// s2m = tanh(sf@Ws2m+b), ss = tanh(sf@Wsuper+b)
__global__ __launch_bounds__(128) void k8a(const float* __restrict__ sfin,
                                           const float* __restrict__ Wz, const float* __restrict__ bz,
                                           const float* __restrict__ Wu, const float* __restrict__ bu,
                                           float* __restrict__ s2m, float* __restrict__ ssb)
{
    const int b = blockIdx.x, g = threadIdx.x;
    __shared__ float s[Hd];
    s[g] = sfin[b * Hd + g];
    __syncthreads();
    float a1 = 0.f, a2 = 0.f;
    for (int h = 0; h < Hd; ++h) { const float v = s[h]; a1 += v * Wz[h * Hd + g]; a2 += v * Wu[h * Hd + g]; }
    s2m[b * Hd + g] = tanhf(a1 + bz[g]);
    ssb[b * Hd + g] = tanhf(a2 + bu[g]);
}

// c_zm2 = s2m@Wzm2+b ; z_super = sig(ss@Wzs1+b + m2s@Wzs2+b); hs = (1-z)*ss + z*m2s
__global__ __launch_bounds__(128) void k8b(const float* __restrict__ s2m, const float* __restrict__ ssb,
                                           const float* __restrict__ m2s,
                                           const float* __restrict__ Wzm2, const float* __restrict__ bzm2,
                                           const float* __restrict__ Wzs1, const float* __restrict__ bzs1,
                                           const float* __restrict__ Wzs2, const float* __restrict__ bzs2,
                                           float* __restrict__ c_zm2, float* __restrict__ hsb)
{
    const int b = blockIdx.x, g = threadIdx.x;
    __shared__ float a[Hd], c[Hd], m[Hd];
    a[g] = s2m[b * Hd + g]; c[g] = ssb[b * Hd + g]; m[g] = m2s[b * Hd + g];
    __syncthreads();
    float x1 = 0.f, x2 = 0.f, x3 = 0.f;
    for (int h = 0; h < Hd; ++h) {
        x1 += a[h] * Wzm2[h * Hd + g];
        x2 += c[h] * Wzs1[h * Hd + g];
        x3 += m[h] * Wzs2[h * Hd + g];
    }
    c_zm2[b * Hd + g] = x1 + bzm2[g];
    const float zs = sigmoidf(x2 + bzs1[g] + x3 + bzs2[g]);
    hsb[b * Hd + g] = (1.f - zs) * c[g] + zs * m[g];
}

// GRU combine: vf_new = (1-sig(zp))*tanh(inn + sig(rp)*hn) + sig(zp)*h
__global__ __launch_bounds__(256) void k_comb(const float* __restrict__ rp,
                                              const float* __restrict__ zp,
                                              const float* __restrict__ innp,
                                              const float* __restrict__ hnp,
                                              const float* __restrict__ hprev,
                                              float* __restrict__ out)
{
    const long i = (long)blockIdx.x * 256 + threadIdx.x;
    const float r = sigmoidf(rp[i]);
    const float z = sigmoidf(zp[i]);
    const float n = tanhf(innp[i] + r * hnp[i]);
    out[i] = (1.f - z) * n + z * hprev[i];
}

// full GRU for the super node (B rows)
__global__ __launch_bounds__(128) void k_gru_s(const float* __restrict__ hs,
                                               const float* __restrict__ sfin,
                                               const float* __restrict__ wih,
                                               const float* __restrict__ whh,
                                               const float* __restrict__ bih,
                                               const float* __restrict__ bhh,
                                               float* __restrict__ sfout)
{
    const int b = blockIdx.x, g = threadIdx.x;
    __shared__ float xs[Hd], hh[Hd];
    xs[g] = hs[b * Hd + g];
    hh[g] = sfin[b * Hd + g];
    __syncthreads();
    float ir = 0.f, iz = 0.f, in_ = 0.f, hr = 0.f, hz = 0.f, hn = 0.f;
    for (int j = 0; j < Hd; ++j) {
        const float x = xs[j], h = hh[j];
        ir += x * wih[j * 384 + g];       iz += x * wih[j * 384 + 128 + g];  in_ += x * wih[j * 384 + 256 + g];
        hr += h * whh[j * 384 + g];       hz += h * whh[j * 384 + 128 + g];  hn  += h * whh[j * 384 + 256 + g];
    }
    const float r = sigmoidf(ir + bih[g] + hr + bhh[g]);
    const float z = sigmoidf(iz + bih[128 + g] + hz + bhh[128 + g]);
    const float n = tanhf(in_ + bih[256 + g] + r * (hn + bhh[256 + g]));
    sfout[b * Hd + g] = (1.f - z) * n + z * hh[g];
}

__global__ __launch_bounds__(256) void k_copy(const float* __restrict__ src,
                                              float* __restrict__ dst, int n)
{
    const int i = blockIdx.x * 256 + threadIdx.x;
    if (i < n) dst[i] = src[i];
}

extern "C" void kernel_launch(void* const* d_in, const int* in_sizes, int n_in,
                              void* d_out, int out_size, void* d_ws, size_t ws_size,
                              hipStream_t stream)
{
    (void)in_sizes; (void)n_in; (void)out_size;

    const float* vertex_mask = (const float*)d_in[1];
    const int*   vertex      = (const int*)d_in[2];
    const int*   edge        = (const int*)d_in[3];
    const int*   atom_adj    = (const int*)d_in[4];
    const int*   bond_adj    = (const int*)d_in[5];
    const float* nbs_mask    = (const float*)d_in[6];
    const float* init_atom   = (const float*)d_in[7];
    const float* init_bond   = (const float*)d_in[8];
    const float* emb_w  = (const float*)d_in[9];
    const float* emb_b  = (const float*)d_in[10];
    const float* Wa_w   = (const float*)d_in[11];
    const float* Wa_b   = (const float*)d_in[12];
    const float* Wbmm_w = (const float*)d_in[13];
    const float* Wbmm_b = (const float*)d_in[14];
    const float* Wm_w   = (const float*)d_in[15];
    const float* Wm_b   = (const float*)d_in[16];
    const float* Wm2s_w = (const float*)d_in[17];
    const float* Wm2s_b = (const float*)d_in[18];
    const float* Ws2m_w = (const float*)d_in[19];
    const float* Ws2m_b = (const float*)d_in[20];
    const float* Wsup_w = (const float*)d_in[21];
    const float* Wsup_b = (const float*)d_in[22];
    const float* Wzm1_w = (const float*)d_in[23];
    const float* Wzm1_b = (const float*)d_in[24];
    const float* Wzm2_w = (const float*)d_in[25];
    const float* Wzm2_b = (const float*)d_in[26];
    const float* Wzs1_w = (const float*)d_in[27];
    const float* Wzs1_b = (const float*)d_in[28];
    const float* Wzs2_w = (const float*)d_in[29];
    const float* Wzs2_b = (const float*)d_in[30];
    const float* U2_w   = (const float*)d_in[31];
    const float* U2_b   = (const float*)d_in[32];
    const float* U1_w   = (const float*)d_in[33];
    const float* U1_b   = (const float*)d_in[34];
    const float* gm_wih = (const float*)d_in[35];
    const float* gm_whh = (const float*)d_in[36];
    const float* gm_bih = (const float*)d_in[37];
    const float* gm_bhh = (const float*)d_in[38];
    const float* gs_wih = (const float*)d_in[39];
    const float* gs_whh = (const float*)d_in[40];
    const float* gs_bih = (const float*)d_in[41];
    const float* gs_bhh = (const float*)d_in[42];

    const size_t BIG = 4194304;  // BN*Hd
    if (ws_size < (5 * BIG + 320000) * sizeof(float)) return;

    float* ws  = (float*)d_ws;
    float* X0  = ws;
    float* Pb  = ws + 1 * BIG;
    float* Qb  = ws + 2 * BIG;
    float* NEI = ws + 3 * BIG;
    float* TMP = ws + 4 * BIG;
    float* S   = ws + 5 * BIG;
    float* sfA    = S;
    float* sfB    = S + 16384;
    float* a_buf  = S + 32768;
    float* attn   = S + 98304;
    float* s_attn = S + 163840;
    float* t_bkh  = S + 164096;
    float* m_vec  = S + 196864;
    float* m2s    = S + 229632;
    float* s2m    = S + 246016;
    float* ssb    = S + 262400;
    float* c_zm2  = S + 278784;
    float* hsb    = S + 295168;

    float* X1 = (float*)d_out;             // vf ping-pong buffer #2 (also final vf)
    float* sf_final = X1 + BIG;            // final sf location

    const dim3 blk(256);
    const dim3 g1024(BN / TR, 1);

    // embed: vf0 = lrelu(init_atom[vertex] @ emb_w + emb_b)
    gemm128<EPI_LRELU><<<g1024, blk, 0, stream>>>(
        init_atom, AFd, AFd, nullptr, 0, 0, vertex,
        emb_w, Hd, nullptr, 0, 0L,
        emb_b, 0L, nullptr,
        X0, 0L, nullptr, nullptr, 0L, nullptr);
    k_sf<<<dim3(B), blk, 0, stream>>>(X0, vertex_mask, sfA);

    for (int d = 0; d < Dd; ++d) {
        float* vin  = (d & 1) ? X1 : X0;
        float* vout = (d & 1) ? X0 : X1;
        float* sin  = (d & 1) ? sfB : sfA;
        float* sout = (d & 1) ? sfA : sfB;

        // a[b,k,n] (tanh GEMM with fused dot-reduce)
        gemm128<EPI_TANHDOT><<<dim3(BN / TR, Kk), blk, 0, stream>>>(
            vin, Hd, Hd, nullptr, 0, 0, nullptr,
            Wa_w + (long)d * Kk * Hd * Hd, Hd, nullptr, 0, (long)Hd * Hd,
            Wa_b + (long)d * Kk * Hd, (long)Hd, nullptr,
            a_buf, (long)Nv,
            sin, Wbmm_w + (long)d * Kk * Hd, (long)Hd, Wbmm_b + (long)d * Kk);
        k_softmax<<<dim3(B * Kk), blk, 0, stream>>>(a_buf, vertex_mask, attn, s_attn);
        k_t<<<dim3(B * Kk), blk, 0, stream>>>(attn, vin, t_bkh);
        k_mvec<<<dim3(B * Kk), dim3(128), 0, stream>>>(t_bkh, s_attn,
            Wm_w + (long)d * Kk * Hd * Hd, Wm_b + (long)d * Kk * Hd, m_vec);
        k_m2s<<<dim3(B), dim3(128), 0, stream>>>(m_vec,
            Wm2s_w + (long)d * Kk * Hd * Hd, Wm2s_b + (long)d * Hd, m2s);

        // P = vf@U2v + b ; Q = edge_init@U2e (gather-GEMM via rowidx)
        gemm128<EPI_NONE><<<g1024, blk, 0, stream>>>(
            vin, Hd, Hd, nullptr, 0, 0, nullptr,
            U2_w + (long)d * (Hd + BFd) * Hd, Hd, nullptr, 0, 0L,
            U2_b + (long)d * Hd, 0L, nullptr,
            Pb, 0L, nullptr, nullptr, 0L, nullptr);
        gemm128<EPI_NONE><<<dim3(BE / TR, 1), blk, 0, stream>>>(
            init_bond, BFd, BFd, nullptr, 0, 0, edge,
            U2_w + (long)d * (Hd + BFd) * Hd + Hd * Hd, Hd, nullptr, 0, 0L,
            nullptr, 0L, nullptr,
            Qb, 0L, nullptr, nullptr, 0L, nullptr);
        k_gather<<<dim3(BN), dim3(128), 0, stream>>>(Pb, Qb, atom_adj, bond_adj, nbs_mask, NEI);

        // main_self = lrelu([vf, nei]@U1 + b)  -> reuse Pb
        gemm128<EPI_LRELU><<<g1024, blk, 0, stream>>>(
            vin, Hd, Hd, NEI, Hd, Hd, nullptr,
            U1_w + (long)d * 2 * Hd * Hd, Hd, nullptr, 0, 0L,
            U1_b + (long)d * Hd, 0L, nullptr,
            Pb, 0L, nullptr, nullptr, 0L, nullptr);

        k8a<<<dim3(B), dim3(128), 0, stream>>>(sin,
            Ws2m_w + (long)d * Hd * Hd, Ws2m_b + (long)d * Hd,
            Wsup_w + (long)d * Hd * Hd, Wsup_b + (long)d * Hd, s2m, ssb);
        k8b<<<dim3(B), dim3(128), 0, stream>>>(s2m, ssb, m2s,
            Wzm2_w + (long)d * Hd * Hd, Wzm2_b + (long)d * Hd,
            Wzs1_w + (long)d * Hd * Hd, Wzs1_b + (long)d * Hd,
            Wzs2_w + (long)d * Hd * Hd, Wzs2_b + (long)d * Hd,
            c_zm2, hsb);

        // z_main GEMM + gate fuse: hidden_main -> Qb
        gemm128<EPI_ZMAIN><<<g1024, blk, 0, stream>>>(
            Pb, Hd, Hd, nullptr, 0, 0, nullptr,
            Wzm1_w + (long)d * Hd * Hd, Hd, nullptr, 0, 0L,
            Wzm1_b + (long)d * Hd, 0L, nullptr,
            Qb, 0L,
            c_zm2, Pb, 0L, s2m);

        // GRU main: r_pre->NEI, z_pre->Pb, inn->vout, hn->TMP
        gemm128<EPI_NONE><<<g1024, blk, 0, stream>>>(
            Qb, Hd, Hd, vin, Hd, Hd, nullptr,
            gm_wih, 3 * Hd, gm_whh, 3 * Hd, 0L,
            gm_bih, 0L, gm_bhh,
            NEI, 0L, nullptr, nullptr, 0L, nullptr);
        gemm128<EPI_NONE><<<g1024, blk, 0, stream>>>(
            Qb, Hd, Hd, vin, Hd, Hd, nullptr,
            gm_wih + Hd, 3 * Hd, gm_whh + Hd, 3 * Hd, 0L,
            gm_bih + Hd, 0L, gm_bhh + Hd,
            Pb, 0L, nullptr, nullptr, 0L, nullptr);
        gemm128<EPI_NONE><<<g1024, blk, 0, stream>>>(
            Qb, Hd, Hd, nullptr, 0, 0, nullptr,
            gm_wih + 2 * Hd, 3 * Hd, nullptr, 0, 0L,
            gm_bih + 2 * Hd, 0L, nullptr,
            vout, 0L, nullptr, nullptr, 0L, nullptr);
        gemm128<EPI_NONE><<<g1024, blk, 0, stream>>>(
            vin, Hd, Hd, nullptr, 0, 0, nullptr,
            gm_whh + 2 * Hd, 3 * Hd, nullptr, 0, 0L,
            gm_bhh + 2 * Hd, 0L, nullptr,
            TMP, 0L, nullptr, nullptr, 0L, nullptr);
        k_comb<<<dim3(BN * Hd / 256), blk, 0, stream>>>(NEI, Pb, vout, TMP, vin, vout);

        // GRU super
        k_gru_s<<<dim3(B), dim3(128), 0, stream>>>(hsb, sin, gs_wih, gs_whh, gs_bih, gs_bhh, sout);
    }

    // final sf (D=3 -> ends in sfB); vf already ends in X1 == d_out
    k_copy<<<dim3(64), blk, 0, stream>>>(sfB, sf_final, B * Hd);
}

// Round 2
// 960.243 us; speedup vs baseline: 1.4868x; 1.4868x over previous
//
#include <hip/hip_runtime.h>

typedef unsigned short ushort_t;
typedef unsigned int uint_t;
typedef __attribute__((ext_vector_type(8))) short short8;
typedef __attribute__((ext_vector_type(4))) float f32x4;

#define B   128
#define Nv  256
#define Mn  12
#define Hd  128
#define Dd  3
#define Kk  2
#define AFd 82
#define BFd 6
#define BN  (B*Nv)   // 32768

enum { EPI_NONE = 0, EPI_LRELU = 1, EPI_TANHDOT = 2, EPI_ZMAIN = 3 };

__device__ __forceinline__ float lrelu(float x) { return x > 0.f ? x : 0.1f * x; }
__device__ __forceinline__ float sigmoidf(float x) { return 1.f / (1.f + expf(-x)); }
__device__ __forceinline__ ushort_t f2b(float x) {
    uint_t u = __float_as_uint(x);
    return (ushort_t)((u + 0x7FFFu + ((u >> 16) & 1u)) >> 16);
}
__device__ __forceinline__ float b2f(ushort_t s) {
    return __uint_as_float(((uint_t)s) << 16);
}

// Transpose-convert weights: Wt[nOut*Kpad + k] = bf16(W[slice*sliceStride + k*ldw + n]),
// zero-padded for k >= K.  nOut = slice*nPerSlice + n.
__global__ __launch_bounds__(256) void k_prep(const float* __restrict__ W,
    int K, int ldw, long sliceStride, int nPerSlice,
    ushort_t* __restrict__ Wt, int Kpad, int total)
{
    int idx = blockIdx.x * 256 + threadIdx.x;
    if (idx >= total) return;
    int nOut = idx / Kpad, k = idx % Kpad;
    int slice = nOut / nPerSlice, n = nOut % nPerSlice;
    float v = (k < K) ? W[(size_t)slice * sliceStride + (size_t)k * ldw + n] : 0.f;
    Wt[idx] = f2b(v);
}

// bf16 MFMA GEMM: out(M x Ncols) = epi( [A1|A2] @ Wt^T + bias )
//  - block tile 128x128, 4 waves (2x2), wave tile 64x64, mfma 16x16x32 bf16
//  - A1: fp32 (ABF=false) or bf16 (ABF=true); A2: optional bf16 concat part
//  - Wt: bf16 [ncolsTotal][Kpad]; blockIdx.y = column block (and weight-slice for TANHDOT)
//  - LDS tiles XOR-swizzled (byte ^= (row&7)<<4) to kill 16-way ds_read_b128 conflicts
template<int EPI, bool ABF, bool OBF>
__global__ __launch_bounds__(256) void mgemm(
    const void* __restrict__ A1v, int lda1, int K1,
    const ushort_t* __restrict__ A2, int lda2, int K2,
    const int* __restrict__ rowidx,
    const ushort_t* __restrict__ Wt, int Kpad,
    const float* __restrict__ b1, long b1sY,
    void* __restrict__ outv, long ldo, long oY,
    const float* __restrict__ e0,
    const float* __restrict__ e1, long e1sY,
    const float* __restrict__ e2,
    const ushort_t* __restrict__ eMS)
{
    const int t    = threadIdx.x;
    const int lane = t & 63;
    const int w    = t >> 6;
    const int wm   = w >> 1, wn = w & 1;
    const int lr   = lane & 15, lg = lane >> 4;
    const int row0 = blockIdx.x * 128;
    const int ky   = blockIdx.y;
    const int Ktot = K1 + K2;

    __shared__ ushort_t As[128 * 64];
    __shared__ ushort_t Bs[128 * 64];
    __shared__ float EUs[128];
    __shared__ float EBb[128];
    __shared__ float red[128][2];

    const ushort_t* Wty = Wt + (size_t)ky * 128 * Kpad;

    f32x4 acc[4][4];
    #pragma unroll
    for (int i = 0; i < 4; ++i)
        #pragma unroll
        for (int j = 0; j < 4; ++j)
            acc[i][j] = (f32x4){0.f, 0.f, 0.f, 0.f};

    const int r_st = t >> 1, half = t & 1;
    const int grow = row0 + r_st;
    const long arow = rowidx ? (long)rowidx[grow] : (long)grow;

    const int nck = Kpad >> 6;
    for (int ck = 0; ck < nck; ++ck) {
        if (ck) __syncthreads();
        // ---- stage A chunk (fp32/bf16 -> bf16 LDS, swizzled) ----
        {
            const int kb = ck * 64 + half * 32;
            union { ushort_t us[32]; uint4 q[4]; } tmp;
            const bool fast1 = ((lda1 & 3) == 0) && (kb + 32 <= K1);
            const bool fast2 = (A2 != nullptr) && (kb >= K1) && (kb + 32 <= Ktot);
            if (ABF && fast1) {
                const ushort_t* src = (const ushort_t*)A1v + (size_t)arow * lda1 + kb;
                #pragma unroll
                for (int v2 = 0; v2 < 4; ++v2) tmp.q[v2] = ((const uint4*)src)[v2];
            } else if (!ABF && fast1) {
                const float* src = (const float*)A1v + (size_t)arow * lda1 + kb;
                #pragma unroll
                for (int v2 = 0; v2 < 8; ++v2) {
                    float4 f = ((const float4*)src)[v2];
                    tmp.us[v2*4+0] = f2b(f.x); tmp.us[v2*4+1] = f2b(f.y);
                    tmp.us[v2*4+2] = f2b(f.z); tmp.us[v2*4+3] = f2b(f.w);
                }
            } else if (fast2) {
                const ushort_t* src = A2 + (size_t)grow * lda2 + (kb - K1);
                #pragma unroll
                for (int v2 = 0; v2 < 4; ++v2) tmp.q[v2] = ((const uint4*)src)[v2];
            } else {
                #pragma unroll
                for (int j = 0; j < 32; ++j) {
                    const int kg = kb + j;
                    ushort_t v = 0;
                    if (kg < K1) {
                        if (ABF) v = ((const ushort_t*)A1v)[(size_t)arow * lda1 + kg];
                        else     v = f2b(((const float*)A1v)[(size_t)arow * lda1 + kg]);
                    } else if (kg < Ktot) {
                        v = A2[(size_t)grow * lda2 + (kg - K1)];
                    }
                    tmp.us[j] = v;
                }
            }
            #pragma unroll
            for (int v2 = 0; v2 < 4; ++v2) {
                int byte = r_st * 128 + (half * 32 + v2 * 8) * 2;
                byte ^= ((r_st & 7) << 4);
                *(uint4*)((char*)As + byte) = tmp.q[v2];
            }
        }
        // ---- stage B chunk (Wt bf16, swizzled) ----
        {
            const ushort_t* src = Wty + (size_t)r_st * Kpad + ck * 64 + half * 32;
            #pragma unroll
            for (int v2 = 0; v2 < 4; ++v2) {
                uint4 wv = ((const uint4*)src)[v2];
                int byte = r_st * 128 + (half * 32 + v2 * 8) * 2;
                byte ^= ((r_st & 7) << 4);
                *(uint4*)((char*)Bs + byte) = wv;
            }
        }
        __syncthreads();
        // ---- MFMA ----
        #pragma unroll
        for (int ks = 0; ks < 64; ks += 32) {
            short8 af[4], bfr[4];
            #pragma unroll
            for (int mf = 0; mf < 4; ++mf) {
                const int row = wm * 64 + mf * 16 + lr;
                int byte = row * 128 + (ks + lg * 8) * 2;
                byte ^= ((row & 7) << 4);
                af[mf] = *(const short8*)((const char*)As + byte);
            }
            #pragma unroll
            for (int nf = 0; nf < 4; ++nf) {
                const int col = wn * 64 + nf * 16 + lr;
                int byte = col * 128 + (ks + lg * 8) * 2;
                byte ^= ((col & 7) << 4);
                bfr[nf] = *(const short8*)((const char*)Bs + byte);
            }
            #pragma unroll
            for (int mf = 0; mf < 4; ++mf)
                #pragma unroll
                for (int nf = 0; nf < 4; ++nf)
                    acc[mf][nf] = __builtin_amdgcn_mfma_f32_16x16x32_bf16(
                        af[mf], bfr[nf], acc[mf][nf], 0, 0, 0);
        }
    }

    // ---- epilogue ----
    if constexpr (EPI == EPI_TANHDOT) {
        __syncthreads();
        if (t < 128) {
            const int b = row0 >> 8;
            EUs[t] = e0[b * Hd + t] * e1[(size_t)ky * e1sY + t];
            EBb[t] = b1[(size_t)ky * b1sY + t];
        }
        __syncthreads();
        #pragma unroll
        for (int mf = 0; mf < 4; ++mf) {
            #pragma unroll
            for (int reg = 0; reg < 4; ++reg) {
                float p = 0.f;
                #pragma unroll
                for (int nf = 0; nf < 4; ++nf) {
                    const int c = wn * 64 + nf * 16 + lr;
                    p += tanhf(acc[mf][nf][reg] + EBb[c]) * EUs[c];
                }
                p += __shfl_xor(p, 1); p += __shfl_xor(p, 2);
                p += __shfl_xor(p, 4); p += __shfl_xor(p, 8);
                if (lr == 0) red[wm * 64 + mf * 16 + lg * 4 + reg][wn] = p;
            }
        }
        __syncthreads();
        if (t < 128) {
            const int gr = row0 + t;
            const float a = red[t][0] + red[t][1] + e2[ky];
            ((float*)outv)[(size_t)(gr >> 8) * (Kk * Nv) + (size_t)ky * oY + (gr & 255)] = a;
        }
    } else {
        const int b = row0 >> 8;
        #pragma unroll
        for (int mf = 0; mf < 4; ++mf) {
            #pragma unroll
            for (int nf = 0; nf < 4; ++nf) {
                const int c = wn * 64 + nf * 16 + lr;
                #pragma unroll
                for (int reg = 0; reg < 4; ++reg) {
                    const int r = wm * 64 + mf * 16 + lg * 4 + reg;
                    const size_t row = (size_t)row0 + r;
                    float v = acc[mf][nf][reg];
                    if (b1) v += b1[(size_t)ky * b1sY + c];
                    if constexpr (EPI == EPI_LRELU) v = lrelu(v);
                    if constexpr (EPI == EPI_ZMAIN) {
                        const float z = sigmoidf(v + e0[b * Hd + c]);
                        const float ms = b2f(eMS[row * Hd + c]);
                        v = (1.f - z) * ms + z * e2[b * Hd + c];
                    }
                    const size_t oidx = row * ldo + (size_t)ky * oY + c;
                    if (OBF) ((ushort_t*)outv)[oidx] = f2b(v);
                    else     ((float*)outv)[oidx] = v;
                }
            }
        }
    }
}

// sf[b,h] = sum_n vf[b,n,h]*vmask[b,n]
__global__ __launch_bounds__(256) void k_sf(const float* __restrict__ vf,
                                            const float* __restrict__ vmask,
                                            float* __restrict__ sf)
{
    const int b = blockIdx.x, t = threadIdx.x;
    const int h = t & 127, half = t >> 7;
    float acc = 0.f;
    for (int n = half * 128; n < half * 128 + 128; ++n)
        acc += vf[((long)b * Nv + n) * Hd + h] * vmask[b * Nv + n];
    __shared__ float red[2][Hd];
    red[half][h] = acc;
    __syncthreads();
    if (t < Hd) sf[b * Hd + t] = red[0][t] + red[1][t];
}

__global__ __launch_bounds__(256) void k_softmax(const float* __restrict__ a,
                                                 const float* __restrict__ vmask,
                                                 float* __restrict__ attn,
                                                 float* __restrict__ s_attn)
{
    const int bk = blockIdx.x, b = bk >> 1, t = threadIdx.x;
    const int wid = t >> 6, lane = t & 63;
    const float v = a[bk * Nv + t];
    float m = v;
    #pragma unroll
    for (int o = 1; o < 64; o <<= 1) m = fmaxf(m, __shfl_xor(m, o));
    __shared__ float lmax[4];
    if (lane == 0) lmax[wid] = m;
    __syncthreads();
    m = fmaxf(fmaxf(lmax[0], lmax[1]), fmaxf(lmax[2], lmax[3]));
    const float e = expf(v - m) * vmask[b * Nv + t];
    float s = e;
    #pragma unroll
    for (int o = 1; o < 64; o <<= 1) s += __shfl_xor(s, o);
    __shared__ float lsum[4];
    if (lane == 0) lsum[wid] = s;
    __syncthreads();
    s = lsum[0] + lsum[1] + lsum[2] + lsum[3];
    const float denom = s + 1e-6f;
    attn[bk * Nv + t] = e / denom;
    if (t == 0) s_attn[bk] = s / denom;
}

__global__ __launch_bounds__(256) void k_t(const float* __restrict__ attn,
                                           const float* __restrict__ vf,
                                           float* __restrict__ tb)
{
    const int bk = blockIdx.x, b = bk >> 1, t = threadIdx.x;
    __shared__ float at[Nv];
    at[t] = attn[bk * Nv + t];
    __syncthreads();
    const int h = t & 127, half = t >> 7;
    float acc = 0.f;
    for (int n = half * 128; n < half * 128 + 128; ++n)
        acc += at[n] * vf[((long)b * Nv + n) * Hd + h];
    __shared__ float red[2][Hd];
    red[half][h] = acc;
    __syncthreads();
    if (t < Hd) tb[bk * Hd + t] = red[0][t] + red[1][t];
}

__global__ __launch_bounds__(128) void k_mvec(const float* __restrict__ tb,
                                              const float* __restrict__ s_attn,
                                              const float* __restrict__ Wm,
                                              const float* __restrict__ bm,
                                              float* __restrict__ m_vec)
{
    const int bk = blockIdx.x, g = threadIdx.x, k = bk & 1;
    __shared__ float ts[Hd];
    ts[g] = tb[bk * Hd + g];
    __syncthreads();
    const float* W = Wm + (long)k * Hd * Hd;
    float acc = 0.f;
    for (int h = 0; h < Hd; ++h) acc += ts[h] * W[h * Hd + g];
    m_vec[bk * Hd + g] = acc + s_attn[bk] * bm[k * Hd + g];
}

__global__ __launch_bounds__(128) void k_m2s(const float* __restrict__ m_vec,
                                             const float* __restrict__ W,
                                             const float* __restrict__ bb,
                                             float* __restrict__ m2s)
{
    const int b = blockIdx.x, g = threadIdx.x;
    __shared__ float ms[2 * Hd];
    ms[g] = m_vec[b * 2 * Hd + g];
    ms[g + Hd] = m_vec[b * 2 * Hd + Hd + g];
    __syncthreads();
    float acc = 0.f;
    for (int j = 0; j < 2 * Hd; ++j) acc += ms[j] * W[j * Hd + g];
    m2s[b * Hd + g] = tanhf(acc + bb[g]);
}

// nei_label[bn,h] = sum_m mask*lrelu(P[atom_adj]+Q[bond_adj])   (bf16 in/out)
__global__ __launch_bounds__(128) void k_gather(const ushort_t* __restrict__ P,
                                                const ushort_t* __restrict__ Q,
                                                const int* __restrict__ aadj,
                                                const int* __restrict__ badj,
                                                const float* __restrict__ nmask,
                                                ushort_t* __restrict__ nei)
{
    const int bn = blockIdx.x, h = threadIdx.x;
    __shared__ int ai[Mn];
    __shared__ int bi[Mn];
    __shared__ float mk[Mn];
    if (h < Mn) {
        ai[h] = aadj[(long)bn * Mn + h];
        bi[h] = badj[(long)bn * Mn + h];
        mk[h] = nmask[(long)bn * Mn + h];
    }
    __syncthreads();
    float acc = 0.f;
    #pragma unroll
    for (int m = 0; m < Mn; ++m) {
        const float v = b2f(P[(size_t)ai[m] * Hd + h]) + b2f(Q[(size_t)bi[m] * Hd + h]);
        acc += mk[m] * lrelu(v);
    }
    nei[(size_t)bn * Hd + h] = f2b(acc);
}

__global__ __launch_bounds__(128) void k8a(const float* __restrict__ sfin,
                                           const float* __restrict__ Wz, const float* __restrict__ bz,
                                           const float* __restrict__ Wu, const float* __restrict__ bu,
                                           float* __restrict__ s2m, float* __restrict__ ssb)
{
    const int b = blockIdx.x, g = threadIdx.x;
    __shared__ float s[Hd];
    s[g] = sfin[b * Hd + g];
    __syncthreads();
    float a1 = 0.f, a2 = 0.f;
    for (int h = 0; h < Hd; ++h) { const float v = s[h]; a1 += v * Wz[h * Hd + g]; a2 += v * Wu[h * Hd + g]; }
    s2m[b * Hd + g] = tanhf(a1 + bz[g]);
    ssb[b * Hd + g] = tanhf(a2 + bu[g]);
}

__global__ __launch_bounds__(128) void k8b(const float* __restrict__ s2m, const float* __restrict__ ssb,
                                           const float* __restrict__ m2s,
                                           const float* __restrict__ Wzm2, const float* __restrict__ bzm2,
                                           const float* __restrict__ Wzs1, const float* __restrict__ bzs1,
                                           const float* __restrict__ Wzs2, const float* __restrict__ bzs2,
                                           float* __restrict__ c_zm2, float* __restrict__ hsb)
{
    const int b = blockIdx.x, g = threadIdx.x;
    __shared__ float a[Hd], c[Hd], m[Hd];
    a[g] = s2m[b * Hd + g]; c[g] = ssb[b * Hd + g]; m[g] = m2s[b * Hd + g];
    __syncthreads();
    float x1 = 0.f, x2 = 0.f, x3 = 0.f;
    for (int h = 0; h < Hd; ++h) {
        x1 += a[h] * Wzm2[h * Hd + g];
        x2 += c[h] * Wzs1[h * Hd + g];
        x3 += m[h] * Wzs2[h * Hd + g];
    }
    c_zm2[b * Hd + g] = x1 + bzm2[g];
    const float zs = sigmoidf(x2 + bzs1[g] + x3 + bzs2[g]);
    hsb[b * Hd + g] = (1.f - zs) * c[g] + zs * m[g];
}

// GRU combine from fused gi/gh (bf16 [row][384])
__global__ __launch_bounds__(256) void k_comb(const ushort_t* __restrict__ gi,
                                              const ushort_t* __restrict__ gh,
                                              const float* __restrict__ hprev,
                                              float* __restrict__ out)
{
    const long i = (long)blockIdx.x * 256 + threadIdx.x;
    const long row = i >> 7;
    const int c = (int)(i & 127);
    const size_t b3 = (size_t)row * 384 + c;
    const float ir = b2f(gi[b3]),       hr = b2f(gh[b3]);
    const float iz = b2f(gi[b3 + 128]), hz = b2f(gh[b3 + 128]);
    const float in_= b2f(gi[b3 + 256]), hn = b2f(gh[b3 + 256]);
    const float r = sigmoidf(ir + hr);
    const float z = sigmoidf(iz + hz);
    const float n = tanhf(in_ + r * hn);
    out[i] = (1.f - z) * n + z * hprev[i];
}

__global__ __launch_bounds__(128) void k_gru_s(const float* __restrict__ hs,
                                               const float* __restrict__ sfin,
                                               const float* __restrict__ wih,
                                               const float* __restrict__ whh,
                                               const float* __restrict__ bih,
                                               const float* __restrict__ bhh,
                                               float* __restrict__ sfout)
{
    const int b = blockIdx.x, g = threadIdx.x;
    __shared__ float xs[Hd], hh[Hd];
    xs[g] = hs[b * Hd + g];
    hh[g] = sfin[b * Hd + g];
    __syncthreads();
    float ir = 0.f, iz = 0.f, in_ = 0.f, hr = 0.f, hz = 0.f, hn = 0.f;
    for (int j = 0; j < Hd; ++j) {
        const float x = xs[j], h = hh[j];
        ir += x * wih[j * 384 + g];       iz += x * wih[j * 384 + 128 + g];  in_ += x * wih[j * 384 + 256 + g];
        hr += h * whh[j * 384 + g];       hz += h * whh[j * 384 + 128 + g];  hn  += h * whh[j * 384 + 256 + g];
    }
    const float r = sigmoidf(ir + bih[g] + hr + bhh[g]);
    const float z = sigmoidf(iz + bih[128 + g] + hz + bhh[128 + g]);
    const float n = tanhf(in_ + bih[256 + g] + r * (hn + bhh[256 + g]));
    sfout[b * Hd + g] = (1.f - z) * n + z * hh[g];
}

__global__ __launch_bounds__(256) void k_copy(const float* __restrict__ src,
                                              float* __restrict__ dst, int n)
{
    const int i = blockIdx.x * 256 + threadIdx.x;
    if (i < n) dst[i] = src[i];
}

extern "C" void kernel_launch(void* const* d_in, const int* in_sizes, int n_in,
                              void* d_out, int out_size, void* d_ws, size_t ws_size,
                              hipStream_t stream)
{
    (void)in_sizes; (void)n_in; (void)out_size;

    const float* vertex_mask = (const float*)d_in[1];
    const int*   vertex      = (const int*)d_in[2];
    const int*   edge        = (const int*)d_in[3];
    const int*   atom_adj    = (const int*)d_in[4];
    const int*   bond_adj    = (const int*)d_in[5];
    const float* nbs_mask    = (const float*)d_in[6];
    const float* init_atom   = (const float*)d_in[7];
    const float* init_bond   = (const float*)d_in[8];
    const float* emb_w  = (const float*)d_in[9];
    const float* emb_b  = (const float*)d_in[10];
    const float* Wa_w   = (const float*)d_in[11];
    const float* Wa_b   = (const float*)d_in[12];
    const float* Wbmm_w = (const float*)d_in[13];
    const float* Wbmm_b = (const float*)d_in[14];
    const float* Wm_w   = (const float*)d_in[15];
    const float* Wm_b   = (const float*)d_in[16];
    const float* Wm2s_w = (const float*)d_in[17];
    const float* Wm2s_b = (const float*)d_in[18];
    const float* Ws2m_w = (const float*)d_in[19];
    const float* Ws2m_b = (const float*)d_in[20];
    const float* Wsup_w = (const float*)d_in[21];
    const float* Wsup_b = (const float*)d_in[22];
    const float* Wzm1_w = (const float*)d_in[23];
    const float* Wzm1_b = (const float*)d_in[24];
    const float* Wzm2_w = (const float*)d_in[25];
    const float* Wzm2_b = (const float*)d_in[26];
    const float* Wzs1_w = (const float*)d_in[27];
    const float* Wzs1_b = (const float*)d_in[28];
    const float* Wzs2_w = (const float*)d_in[29];
    const float* Wzs2_b = (const float*)d_in[30];
    const float* U2_w   = (const float*)d_in[31];
    const float* U2_b   = (const float*)d_in[32];
    const float* U1_w   = (const float*)d_in[33];
    const float* U1_b   = (const float*)d_in[34];
    const float* gm_wih = (const float*)d_in[35];
    const float* gm_whh = (const float*)d_in[36];
    const float* gm_bih = (const float*)d_in[37];
    const float* gm_bhh = (const float*)d_in[38];
    const float* gs_wih = (const float*)d_in[39];
    const float* gs_whh = (const float*)d_in[40];
    const float* gs_bih = (const float*)d_in[41];
    const float* gs_bhh = (const float*)d_in[42];

    const size_t MB = 1u << 20;
    if (ws_size < 68 * MB) return;

    char* base = (char*)d_ws;
    float*    X0   = (float*)base;                  // 16 MB fp32 vf ping
    ushort_t* Pb   = (ushort_t*)(base + 16 * MB);   // 8 MB bf16
    ushort_t* Qb   = (ushort_t*)(base + 24 * MB);   // 8 MB
    ushort_t* NEIb = (ushort_t*)(base + 32 * MB);   // 8 MB
    ushort_t* MSb  = (ushort_t*)(base + 40 * MB);   // 8 MB
    ushort_t* HIDb = (ushort_t*)(base + 48 * MB);   // 8 MB (+8 MB spare to 64 MB)
    ushort_t* giB  = Pb;                            // 24 MB overlay (P,Q,NEI dead)
    ushort_t* ghB  = MSb;                           // 24 MB overlay (MS,HID,spare)
    ushort_t* WT   = (ushort_t*)(base + 64 * MB);   // ~0.9 MB bf16 weights
    float*    S    = (float*)(base + 66 * MB);      // small fp32 buffers

    float* sfA    = S;
    float* sfB    = S + 16384;
    float* a_buf  = S + 32768;
    float* attn   = S + 98304;
    float* s_attn = S + 163840;
    float* t_bkh  = S + 164096;
    float* m_vec  = S + 196864;
    float* m2s    = S + 229632;
    float* s2m    = S + 246016;
    float* ssb    = S + 262400;
    float* c_zm2  = S + 278784;
    float* hsb    = S + 295168;

    float* X1 = (float*)d_out;
    float* sf_final = X1 + (size_t)BN * Hd;

    // Wt layout (ushort offsets)
    ushort_t* wt_emb = WT;                           // 128*128
    const int PERD = 106496;                         // per-layer block
    ushort_t* wt_gih = WT + 16384 + 3 * PERD;        // 384*128
    ushort_t* wt_ghh = wt_gih + 49152;               // 384*128

    auto prep = [&](const float* W, int K, int ldw, long sStride, int nPer,
                    ushort_t* Wt_, int Kpad, int ncols) {
        const int total = ncols * Kpad;
        k_prep<<<dim3((total + 255) / 256), dim3(256), 0, stream>>>(
            W, K, ldw, sStride, nPer, Wt_, Kpad, total);
    };

    prep(emb_w, AFd, Hd, 0, Hd, wt_emb, 128, 128);
    for (int d = 0; d < Dd; ++d) {
        ushort_t* wt_wa  = WT + 16384 + d * PERD;
        ushort_t* wt_u2v = wt_wa + 32768;
        ushort_t* wt_u2e = wt_u2v + 16384;
        ushort_t* wt_u1  = wt_u2e + 8192;
        ushort_t* wt_zm1 = wt_u1 + 32768;
        prep(Wa_w + (long)d * Kk * Hd * Hd, Hd, Hd, (long)Hd * Hd, Hd, wt_wa, 128, 256);
        prep(U2_w + (long)d * (Hd + BFd) * Hd, Hd, Hd, 0, Hd, wt_u2v, 128, 128);
        prep(U2_w + (long)d * (Hd + BFd) * Hd + Hd * Hd, BFd, Hd, 0, Hd, wt_u2e, 64, 128);
        prep(U1_w + (long)d * 2 * Hd * Hd, 2 * Hd, Hd, 0, Hd, wt_u1, 256, 128);
        prep(Wzm1_w + (long)d * Hd * Hd, Hd, Hd, 0, Hd, wt_zm1, 128, 128);
    }
    prep(gm_wih, Hd, 3 * Hd, 0, 3 * Hd, wt_gih, 128, 384);
    prep(gm_whh, Hd, 3 * Hd, 0, 3 * Hd, wt_ghh, 128, 384);

    const dim3 blk(256);
    const dim3 g1(BN / 128, 1);

    // embed: vf0 = lrelu(init_atom[vertex] @ emb_w + emb_b)  (fp32 out)
    mgemm<EPI_LRELU, false, false><<<g1, blk, 0, stream>>>(
        init_atom, AFd, AFd, nullptr, 0, 0, vertex,
        wt_emb, 128, emb_b, 0,
        X0, Hd, 0, nullptr, nullptr, 0, nullptr, nullptr);
    k_sf<<<dim3(B), blk, 0, stream>>>(X0, vertex_mask, sfA);

    for (int d = 0; d < Dd; ++d) {
        float* vin  = (d & 1) ? X1 : X0;
        float* vout = (d & 1) ? X0 : X1;
        float* sin  = (d & 1) ? sfB : sfA;
        float* sout = (d & 1) ? sfA : sfB;

        ushort_t* wt_wa  = WT + 16384 + d * PERD;
        ushort_t* wt_u2v = wt_wa + 32768;
        ushort_t* wt_u2e = wt_u2v + 16384;
        ushort_t* wt_u1  = wt_u2e + 8192;
        ushort_t* wt_zm1 = wt_u1 + 32768;

        // a[b,k,n]: tanh GEMM + fused dot-reduce
        mgemm<EPI_TANHDOT, false, false><<<dim3(BN / 128, Kk), blk, 0, stream>>>(
            vin, Hd, Hd, nullptr, 0, 0, nullptr,
            wt_wa, 128,
            Wa_b + (long)d * Kk * Hd, Hd,
            a_buf, 0, Nv,
            sin, Wbmm_w + (long)d * Kk * Hd, Hd, Wbmm_b + (long)d * Kk, nullptr);
        k_softmax<<<dim3(B * Kk), blk, 0, stream>>>(a_buf, vertex_mask, attn, s_attn);
        k_t<<<dim3(B * Kk), blk, 0, stream>>>(attn, vin, t_bkh);
        k_mvec<<<dim3(B * Kk), dim3(128), 0, stream>>>(t_bkh, s_attn,
            Wm_w + (long)d * Kk * Hd * Hd, Wm_b + (long)d * Kk * Hd, m_vec);
        k_m2s<<<dim3(B), dim3(128), 0, stream>>>(m_vec,
            Wm2s_w + (long)d * Kk * Hd * Hd, Wm2s_b + (long)d * Hd, m2s);

        // P = vf@U2v + b (bf16); Q = bond_init[edge]@U2e (bf16)
        mgemm<EPI_NONE, false, true><<<g1, blk, 0, stream>>>(
            vin, Hd, Hd, nullptr, 0, 0, nullptr,
            wt_u2v, 128, U2_b + (long)d * Hd, 0,
            Pb, Hd, 0, nullptr, nullptr, 0, nullptr, nullptr);
        mgemm<EPI_NONE, false, true><<<g1, blk, 0, stream>>>(
            init_bond, BFd, BFd, nullptr, 0, 0, edge,
            wt_u2e, 64, nullptr, 0,
            Qb, Hd, 0, nullptr, nullptr, 0, nullptr, nullptr);
        k_gather<<<dim3(BN), dim3(128), 0, stream>>>(Pb, Qb, atom_adj, bond_adj, nbs_mask, NEIb);

        // main_self = lrelu([vf, nei]@U1 + b)  -> MS bf16
        mgemm<EPI_LRELU, false, true><<<g1, blk, 0, stream>>>(
            vin, Hd, Hd, NEIb, Hd, Hd, nullptr,
            wt_u1, 256, U1_b + (long)d * Hd, 0,
            MSb, Hd, 0, nullptr, nullptr, 0, nullptr, nullptr);

        k8a<<<dim3(B), dim3(128), 0, stream>>>(sin,
            Ws2m_w + (long)d * Hd * Hd, Ws2m_b + (long)d * Hd,
            Wsup_w + (long)d * Hd * Hd, Wsup_b + (long)d * Hd, s2m, ssb);
        k8b<<<dim3(B), dim3(128), 0, stream>>>(s2m, ssb, m2s,
            Wzm2_w + (long)d * Hd * Hd, Wzm2_b + (long)d * Hd,
            Wzs1_w + (long)d * Hd * Hd, Wzs1_b + (long)d * Hd,
            Wzs2_w + (long)d * Hd * Hd, Wzs2_b + (long)d * Hd,
            c_zm2, hsb);

        // hidden_main = (1-z)*MS + z*s2m  -> HID bf16
        mgemm<EPI_ZMAIN, true, true><<<g1, blk, 0, stream>>>(
            MSb, Hd, Hd, nullptr, 0, 0, nullptr,
            wt_zm1, 128, Wzm1_b + (long)d * Hd, 0,
            HIDb, Hd, 0,
            c_zm2, nullptr, 0, s2m, MSb);

        // GRU main: gi = HID@wih + bih ; gh = vf@whh + bhh  (both bf16 [row][384])
        mgemm<EPI_NONE, true, true><<<dim3(BN / 128, 3), blk, 0, stream>>>(
            HIDb, Hd, Hd, nullptr, 0, 0, nullptr,
            wt_gih, 128, gm_bih, 128,
            giB, 3 * Hd, 128, nullptr, nullptr, 0, nullptr, nullptr);
        mgemm<EPI_NONE, false, true><<<dim3(BN / 128, 3), blk, 0, stream>>>(
            vin, Hd, Hd, nullptr, 0, 0, nullptr,
            wt_ghh, 128, gm_bhh, 128,
            ghB, 3 * Hd, 128, nullptr, nullptr, 0, nullptr, nullptr);
        k_comb<<<dim3(BN * Hd / 256), blk, 0, stream>>>(giB, ghB, vin, vout);

        k_gru_s<<<dim3(B), dim3(128), 0, stream>>>(hsb, sin, gs_wih, gs_whh, gs_bih, gs_bhh, sout);
    }

    k_copy<<<dim3((B * Hd + 255) / 256), blk, 0, stream>>>(sfB, sf_final, B * Hd);
}

// Round 3
// 661.493 us; speedup vs baseline: 2.1583x; 1.4516x over previous
//
#include <hip/hip_runtime.h>

typedef unsigned short ushort_t;
typedef unsigned int uint_t;
typedef __attribute__((ext_vector_type(8))) short short8;
typedef __attribute__((ext_vector_type(4))) float f32x4;

#define B   128
#define Nv  256
#define Mn  12
#define Hd  128
#define Dd  3
#define Kk  2
#define AFd 82
#define BFd 6
#define BN  (B*Nv)   // 32768

enum { EPI_NONE = 0, EPI_LRELU = 1, EPI_TANHDOT = 2, EPI_ZMAIN = 3 };

__device__ __forceinline__ float lrelu(float x) { return x > 0.f ? x : 0.1f * x; }
__device__ __forceinline__ float sigmoidf(float x) { return 1.f / (1.f + expf(-x)); }
__device__ __forceinline__ ushort_t f2b(float x) {
    uint_t u = __float_as_uint(x);
    return (ushort_t)((u + 0x7FFFu + ((u >> 16) & 1u)) >> 16);
}
__device__ __forceinline__ float b2f(ushort_t s) {
    return __uint_as_float(((uint_t)s) << 16);
}

// ---------------- fused weight prep (one launch) ----------------
struct PrepJob {
    const float* W;
    long sliceStride;
    int K, ldw, nPerSlice, Kpad, total, outOff, blockStart;
};
struct PrepJobs { PrepJob j[18]; int nJobs; };

__global__ __launch_bounds__(256) void k_prep_all(PrepJobs P, ushort_t* __restrict__ WT)
{
    int bid = blockIdx.x;
    int ji = 0;
    #pragma unroll 1
    while (ji + 1 < P.nJobs && P.j[ji + 1].blockStart <= bid) ++ji;
    const PrepJob J = P.j[ji];
    const int idx = (bid - J.blockStart) * 256 + threadIdx.x;
    if (idx >= J.total) return;
    const int nOut = idx / J.Kpad, k = idx % J.Kpad;
    const int slice = nOut / J.nPerSlice, n = nOut % J.nPerSlice;
    float v = (k < J.K) ? J.W[(size_t)slice * J.sliceStride + (size_t)k * J.ldw + n] : 0.f;
    WT[J.outOff + idx] = f2b(v);
}

// ---------------- bf16 MFMA GEMM (128x128 tile, 4 waves) ----------------
template<int EPI, bool ABF, bool OBF>
__global__ __launch_bounds__(256) void mgemm(
    const void* __restrict__ A1v, int lda1, int K1,
    const ushort_t* __restrict__ A2, int lda2, int K2,
    const int* __restrict__ rowidx,
    const ushort_t* __restrict__ Wt, int Kpad,
    const float* __restrict__ b1, long b1sY,
    void* __restrict__ outv, long ldo, long oY,
    const float* __restrict__ e0,
    const float* __restrict__ e1, long e1sY,
    const float* __restrict__ e2,
    const ushort_t* __restrict__ eMS)
{
    const int t    = threadIdx.x;
    const int lane = t & 63;
    const int w    = t >> 6;
    const int wm   = w >> 1, wn = w & 1;
    const int lr   = lane & 15, lg = lane >> 4;
    const int row0 = blockIdx.x * 128;
    const int ky   = blockIdx.y;
    const int Ktot = K1 + K2;

    __shared__ ushort_t As[128 * 64];
    __shared__ ushort_t Bs[128 * 64];
    __shared__ float EUs[128];
    __shared__ float EBb[128];
    __shared__ float red[128][2];

    const ushort_t* Wty = Wt + (size_t)ky * 128 * Kpad;

    f32x4 acc[4][4];
    #pragma unroll
    for (int i = 0; i < 4; ++i)
        #pragma unroll
        for (int j = 0; j < 4; ++j)
            acc[i][j] = (f32x4){0.f, 0.f, 0.f, 0.f};

    const int r_st = t >> 1, half = t & 1;
    const int grow = row0 + r_st;
    const long arow = rowidx ? (long)rowidx[grow] : (long)grow;

    const int nck = Kpad >> 6;
    for (int ck = 0; ck < nck; ++ck) {
        if (ck) __syncthreads();
        // ---- stage A chunk ----
        {
            const int kb = ck * 64 + half * 32;
            union { ushort_t us[32]; uint4 q[4]; } tmp;
            const bool fast1 = ((lda1 & 3) == 0) && (kb + 32 <= K1);
            const bool fast2 = (A2 != nullptr) && (kb >= K1) && (kb + 32 <= Ktot);
            if (ABF && fast1) {
                const ushort_t* src = (const ushort_t*)A1v + (size_t)arow * lda1 + kb;
                #pragma unroll
                for (int v2 = 0; v2 < 4; ++v2) tmp.q[v2] = ((const uint4*)src)[v2];
            } else if (!ABF && fast1) {
                const float* src = (const float*)A1v + (size_t)arow * lda1 + kb;
                #pragma unroll
                for (int v2 = 0; v2 < 8; ++v2) {
                    float4 f = ((const float4*)src)[v2];
                    tmp.us[v2*4+0] = f2b(f.x); tmp.us[v2*4+1] = f2b(f.y);
                    tmp.us[v2*4+2] = f2b(f.z); tmp.us[v2*4+3] = f2b(f.w);
                }
            } else if (fast2) {
                const ushort_t* src = A2 + (size_t)grow * lda2 + (kb - K1);
                #pragma unroll
                for (int v2 = 0; v2 < 4; ++v2) tmp.q[v2] = ((const uint4*)src)[v2];
            } else {
                #pragma unroll
                for (int j = 0; j < 32; ++j) {
                    const int kg = kb + j;
                    ushort_t v = 0;
                    if (kg < K1) {
                        if (ABF) v = ((const ushort_t*)A1v)[(size_t)arow * lda1 + kg];
                        else     v = f2b(((const float*)A1v)[(size_t)arow * lda1 + kg]);
                    } else if (kg < Ktot) {
                        v = A2[(size_t)grow * lda2 + (kg - K1)];
                    }
                    tmp.us[j] = v;
                }
            }
            #pragma unroll
            for (int v2 = 0; v2 < 4; ++v2) {
                int byte = r_st * 128 + (half * 32 + v2 * 8) * 2;
                byte ^= ((r_st & 7) << 4);
                *(uint4*)((char*)As + byte) = tmp.q[v2];
            }
        }
        // ---- stage B chunk ----
        {
            const ushort_t* src = Wty + (size_t)r_st * Kpad + ck * 64 + half * 32;
            #pragma unroll
            for (int v2 = 0; v2 < 4; ++v2) {
                uint4 wv = ((const uint4*)src)[v2];
                int byte = r_st * 128 + (half * 32 + v2 * 8) * 2;
                byte ^= ((r_st & 7) << 4);
                *(uint4*)((char*)Bs + byte) = wv;
            }
        }
        __syncthreads();
        // ---- MFMA ----
        #pragma unroll
        for (int ks = 0; ks < 64; ks += 32) {
            short8 af[4], bfr[4];
            #pragma unroll
            for (int mf = 0; mf < 4; ++mf) {
                const int row = wm * 64 + mf * 16 + lr;
                int byte = row * 128 + (ks + lg * 8) * 2;
                byte ^= ((row & 7) << 4);
                af[mf] = *(const short8*)((const char*)As + byte);
            }
            #pragma unroll
            for (int nf = 0; nf < 4; ++nf) {
                const int col = wn * 64 + nf * 16 + lr;
                int byte = col * 128 + (ks + lg * 8) * 2;
                byte ^= ((col & 7) << 4);
                bfr[nf] = *(const short8*)((const char*)Bs + byte);
            }
            #pragma unroll
            for (int mf = 0; mf < 4; ++mf)
                #pragma unroll
                for (int nf = 0; nf < 4; ++nf)
                    acc[mf][nf] = __builtin_amdgcn_mfma_f32_16x16x32_bf16(
                        af[mf], bfr[nf], acc[mf][nf], 0, 0, 0);
        }
    }

    // ---- epilogue ----
    if constexpr (EPI == EPI_TANHDOT) {
        __syncthreads();
        if (t < 128) {
            const int b = row0 >> 8;
            EUs[t] = e0[b * Hd + t] * e1[(size_t)ky * e1sY + t];
            EBb[t] = b1[(size_t)ky * b1sY + t];
        }
        __syncthreads();
        #pragma unroll
        for (int mf = 0; mf < 4; ++mf) {
            #pragma unroll
            for (int reg = 0; reg < 4; ++reg) {
                float p = 0.f;
                #pragma unroll
                for (int nf = 0; nf < 4; ++nf) {
                    const int c = wn * 64 + nf * 16 + lr;
                    p += tanhf(acc[mf][nf][reg] + EBb[c]) * EUs[c];
                }
                p += __shfl_xor(p, 1); p += __shfl_xor(p, 2);
                p += __shfl_xor(p, 4); p += __shfl_xor(p, 8);
                if (lr == 0) red[wm * 64 + mf * 16 + lg * 4 + reg][wn] = p;
            }
        }
        __syncthreads();
        if (t < 128) {
            const int gr = row0 + t;
            const float a = red[t][0] + red[t][1] + e2[ky];
            ((float*)outv)[(size_t)(gr >> 8) * (Kk * Nv) + (size_t)ky * oY + (gr & 255)] = a;
        }
    } else {
        const int b = row0 >> 8;
        #pragma unroll
        for (int mf = 0; mf < 4; ++mf) {
            #pragma unroll
            for (int nf = 0; nf < 4; ++nf) {
                const int c = wn * 64 + nf * 16 + lr;
                #pragma unroll
                for (int reg = 0; reg < 4; ++reg) {
                    const int r = wm * 64 + mf * 16 + lg * 4 + reg;
                    const size_t row = (size_t)row0 + r;
                    float v = acc[mf][nf][reg];
                    if (b1) v += b1[(size_t)ky * b1sY + c];
                    if constexpr (EPI == EPI_LRELU) v = lrelu(v);
                    if constexpr (EPI == EPI_ZMAIN) {
                        const float z = sigmoidf(v + e0[b * Hd + c]);
                        const float ms = b2f(eMS[row * Hd + c]);
                        v = (1.f - z) * ms + z * e2[b * Hd + c];
                    }
                    const size_t oidx = row * ldo + (size_t)ky * oY + c;
                    if (OBF) ((ushort_t*)outv)[oidx] = f2b(v);
                    else     ((float*)outv)[oidx] = v;
                }
            }
        }
    }
}

// ---------------- latency-optimized GEMV building block ----------------
// 256 threads: y[g] = sum_{h<K} x[h] * W[h*ldw + off + g], g in [0,128)
// float4 along g (coalesced), 8-way K-split, LDS tree reduce.
__device__ __forceinline__ void gemv128(const float* __restrict__ W, int ldw, int off,
                                        const float* __restrict__ x, int K,
                                        float (*red)[32][4], float* __restrict__ y, int t)
{
    const int gq = t & 31, hs = t >> 5;
    const int hn = K >> 3;
    f32x4 acc = (f32x4){0.f, 0.f, 0.f, 0.f};
    const float* Wp = W + (size_t)off + (size_t)gq * 4;
    const int h0 = hs * hn;
    #pragma unroll 8
    for (int i = 0; i < hn; ++i) {
        const float4 wv = *(const float4*)&Wp[(size_t)(h0 + i) * ldw];
        const float xv = x[h0 + i];
        acc.x = fmaf(xv, wv.x, acc.x);
        acc.y = fmaf(xv, wv.y, acc.y);
        acc.z = fmaf(xv, wv.z, acc.z);
        acc.w = fmaf(xv, wv.w, acc.w);
    }
    *(f32x4*)&red[hs][gq][0] = acc;
    __syncthreads();
    if (t < 128) {
        float s = 0.f;
        #pragma unroll
        for (int p = 0; p < 8; ++p) s += red[p][t >> 2][t & 3];
        y[t] = s;
    }
    __syncthreads();
}

// ---------------- fused supernode chain, one block per b ----------------
// attn -> (s_attn, t) -> m_vec -> m2s ; sf -> s2m, ss -> c_zm2, z_super,
// hidden_super -> super GRU -> sf_out.  Exports s2m, c_zm2 (for ZMAIN GEMM).
__global__ __launch_bounds__(256) void k_super(
    const float* __restrict__ attn, const float* __restrict__ vf,
    const float* __restrict__ sf_in,
    const float* __restrict__ Wm, const float* __restrict__ bm,
    const float* __restrict__ Wm2s, const float* __restrict__ bm2s,
    const float* __restrict__ Ws2m, const float* __restrict__ bs2m,
    const float* __restrict__ Wsup, const float* __restrict__ bsup,
    const float* __restrict__ Wzm2, const float* __restrict__ bzm2,
    const float* __restrict__ Wzs1, const float* __restrict__ bzs1,
    const float* __restrict__ Wzs2, const float* __restrict__ bzs2,
    const float* __restrict__ gwih, const float* __restrict__ gwhh,
    const float* __restrict__ gbih, const float* __restrict__ gbhh,
    float* __restrict__ s2m_g, float* __restrict__ czm2_g,
    float* __restrict__ sf_out)
{
    const int b = blockIdx.x, t = threadIdx.x;
    __shared__ float red[8][32][4];
    __shared__ float att0[256], att1[256];
    __shared__ float sfl[128], tbA[128], tbB[128], mv[256];
    __shared__ float ms2[128], s2ml[128], ssl[128], hsl[128], tmp1[128], tmp2[128];
    __shared__ float gib[384], ghb[384];
    __shared__ float saS[2];

    att0[t] = attn[(size_t)b * 512 + t];
    att1[t] = attn[(size_t)b * 512 + 256 + t];
    if (t < 128) sfl[t] = sf_in[b * Hd + t];
    __syncthreads();

    // s_attn[k] = sum_n attn[k][n]
    if (t < 128) {
        const float* a = (t < 64) ? att0 : att1;
        const int l = t & 63;
        float s = a[l] + a[l + 64] + a[l + 128] + a[l + 192];
        #pragma unroll
        for (int o = 1; o < 64; o <<= 1) s += __shfl_xor(s, o);
        if (l == 0) saS[t >> 6] = s;
    }
    __syncthreads();

    // t[k,h] = sum_n attn[k,n] * vf[b,n,h]  (dual pass over vf)
    {
        const int hq = t & 31, ns = t >> 5;
        f32x4 a0 = (f32x4){0.f,0.f,0.f,0.f}, a1 = (f32x4){0.f,0.f,0.f,0.f};
        const float* base = vf + (size_t)b * Nv * Hd + hq * 4;
        #pragma unroll 8
        for (int i = 0; i < 32; ++i) {
            const int n = ns * 32 + i;
            const float4 v = *(const float4*)&base[(size_t)n * Hd];
            const float w0 = att0[n], w1 = att1[n];
            a0.x = fmaf(w0, v.x, a0.x); a0.y = fmaf(w0, v.y, a0.y);
            a0.z = fmaf(w0, v.z, a0.z); a0.w = fmaf(w0, v.w, a0.w);
            a1.x = fmaf(w1, v.x, a1.x); a1.y = fmaf(w1, v.y, a1.y);
            a1.z = fmaf(w1, v.z, a1.z); a1.w = fmaf(w1, v.w, a1.w);
        }
        *(f32x4*)&red[ns][hq][0] = a0;
        __syncthreads();
        if (t < 128) { float s = 0.f;
            #pragma unroll
            for (int p = 0; p < 8; ++p) s += red[p][t >> 2][t & 3];
            tbA[t] = s; }
        __syncthreads();
        *(f32x4*)&red[ns][hq][0] = a1;
        __syncthreads();
        if (t < 128) { float s = 0.f;
            #pragma unroll
            for (int p = 0; p < 8; ++p) s += red[p][t >> 2][t & 3];
            tbB[t] = s; }
        __syncthreads();
    }

    // m_vec[k,g] = t[k]@Wm[k] + s_attn[k]*bm[k]
    gemv128(Wm, Hd, 0, tbA, Hd, red, mv, t);
    gemv128(Wm + Hd * Hd, Hd, 0, tbB, Hd, red, mv + 128, t);
    mv[t] += saS[t >> 7] * bm[t];
    __syncthreads();

    // m2s = tanh(m_vec @ Wm2s + b)   (K=256)
    gemv128(Wm2s, Hd, 0, mv, 2 * Hd, red, tmp1, t);
    if (t < 128) ms2[t] = tanhf(tmp1[t] + bm2s[t]);
    __syncthreads();

    // s2m, ss
    gemv128(Ws2m, Hd, 0, sfl, Hd, red, tmp1, t);
    if (t < 128) { const float v = tanhf(tmp1[t] + bs2m[t]); s2ml[t] = v; s2m_g[b * Hd + t] = v; }
    __syncthreads();
    gemv128(Wsup, Hd, 0, sfl, Hd, red, tmp1, t);
    if (t < 128) ssl[t] = tanhf(tmp1[t] + bsup[t]);
    __syncthreads();

    // c_zm2 = s2m@Wzm2 + b (export)
    gemv128(Wzm2, Hd, 0, s2ml, Hd, red, tmp1, t);
    if (t < 128) czm2_g[b * Hd + t] = tmp1[t] + bzm2[t];

    // z_super, hidden_super
    gemv128(Wzs1, Hd, 0, ssl, Hd, red, tmp1, t);
    gemv128(Wzs2, Hd, 0, ms2, Hd, red, tmp2, t);
    if (t < 128) {
        const float zs = sigmoidf(tmp1[t] + bzs1[t] + tmp2[t] + bzs2[t]);
        hsl[t] = (1.f - zs) * ssl[t] + zs * ms2[t];
    }
    __syncthreads();

    // super GRU
    #pragma unroll 1
    for (int c = 0; c < 3; ++c) {
        gemv128(gwih, 3 * Hd, c * Hd, hsl, Hd, red, tmp1, t);
        if (t < 128) gib[c * Hd + t] = tmp1[t] + gbih[c * Hd + t];
        gemv128(gwhh, 3 * Hd, c * Hd, sfl, Hd, red, tmp2, t);
        if (t < 128) ghb[c * Hd + t] = tmp2[t] + gbhh[c * Hd + t];
    }
    __syncthreads();
    if (t < 128) {
        const float r = sigmoidf(gib[t] + ghb[t]);
        const float z = sigmoidf(gib[128 + t] + ghb[128 + t]);
        const float n = tanhf(gib[256 + t] + r * ghb[256 + t]);
        sf_out[b * Hd + t] = (1.f - z) * n + z * sfl[t];
    }
}

// sf[b,h] = sum_n vf[b,n,h]*vmask[b,n]  (vectorized)
__global__ __launch_bounds__(256) void k_sfv(const float* __restrict__ vf,
                                             const float* __restrict__ vmask,
                                             float* __restrict__ sf)
{
    const int b = blockIdx.x, t = threadIdx.x;
    __shared__ float vm[256];
    __shared__ float red[8][32][4];
    vm[t] = vmask[b * Nv + t];
    __syncthreads();
    const int hq = t & 31, ns = t >> 5;
    f32x4 acc = (f32x4){0.f,0.f,0.f,0.f};
    const float* base = vf + (size_t)b * Nv * Hd + hq * 4;
    #pragma unroll 8
    for (int i = 0; i < 32; ++i) {
        const int n = ns * 32 + i;
        const float4 v = *(const float4*)&base[(size_t)n * Hd];
        const float w = vm[n];
        acc.x = fmaf(w, v.x, acc.x); acc.y = fmaf(w, v.y, acc.y);
        acc.z = fmaf(w, v.z, acc.z); acc.w = fmaf(w, v.w, acc.w);
    }
    *(f32x4*)&red[ns][hq][0] = acc;
    __syncthreads();
    if (t < 128) {
        float s = 0.f;
        #pragma unroll
        for (int p = 0; p < 8; ++p) s += red[p][t >> 2][t & 3];
        sf[b * Hd + t] = s;
    }
}

__global__ __launch_bounds__(256) void k_softmax(const float* __restrict__ a,
                                                 const float* __restrict__ vmask,
                                                 float* __restrict__ attn)
{
    const int bk = blockIdx.x, b = bk >> 1, t = threadIdx.x;
    const int wid = t >> 6, lane = t & 63;
    const float v = a[bk * Nv + t];
    float m = v;
    #pragma unroll
    for (int o = 1; o < 64; o <<= 1) m = fmaxf(m, __shfl_xor(m, o));
    __shared__ float lmax[4];
    if (lane == 0) lmax[wid] = m;
    __syncthreads();
    m = fmaxf(fmaxf(lmax[0], lmax[1]), fmaxf(lmax[2], lmax[3]));
    const float e = expf(v - m) * vmask[b * Nv + t];
    float s = e;
    #pragma unroll
    for (int o = 1; o < 64; o <<= 1) s += __shfl_xor(s, o);
    __shared__ float lsum[4];
    if (lane == 0) lsum[wid] = s;
    __syncthreads();
    s = lsum[0] + lsum[1] + lsum[2] + lsum[3];
    attn[bk * Nv + t] = e / (s + 1e-6f);
}

// nei_label: 2 bn per block
__global__ __launch_bounds__(256) void k_gather(const ushort_t* __restrict__ P,
                                                const ushort_t* __restrict__ Q,
                                                const int* __restrict__ aadj,
                                                const int* __restrict__ badj,
                                                const float* __restrict__ nmask,
                                                ushort_t* __restrict__ nei)
{
    const int sub = threadIdx.x >> 7;
    const int bn = blockIdx.x * 2 + sub;
    const int h = threadIdx.x & 127;
    __shared__ int ai[2][Mn];
    __shared__ int bi[2][Mn];
    __shared__ float mk[2][Mn];
    if (h < Mn) {
        ai[sub][h] = aadj[(long)bn * Mn + h];
        bi[sub][h] = badj[(long)bn * Mn + h];
        mk[sub][h] = nmask[(long)bn * Mn + h];
    }
    __syncthreads();
    float acc = 0.f;
    #pragma unroll
    for (int m = 0; m < Mn; ++m) {
        const float v = b2f(P[(size_t)ai[sub][m] * Hd + h]) + b2f(Q[(size_t)bi[sub][m] * Hd + h]);
        acc += mk[sub][m] * lrelu(v);
    }
    nei[(size_t)bn * Hd + h] = f2b(acc);
}

// GRU combine from fused gi/gh (bf16 [row][384])
__global__ __launch_bounds__(256) void k_comb(const ushort_t* __restrict__ gi,
                                              const ushort_t* __restrict__ gh,
                                              const float* __restrict__ hprev,
                                              float* __restrict__ out)
{
    const long i = (long)blockIdx.x * 256 + threadIdx.x;
    const long row = i >> 7;
    const int c = (int)(i & 127);
    const size_t b3 = (size_t)row * 384 + c;
    const float ir = b2f(gi[b3]),       hr = b2f(gh[b3]);
    const float iz = b2f(gi[b3 + 128]), hz = b2f(gh[b3 + 128]);
    const float in_= b2f(gi[b3 + 256]), hn = b2f(gh[b3 + 256]);
    const float r = sigmoidf(ir + hr);
    const float z = sigmoidf(iz + hz);
    const float n = tanhf(in_ + r * hn);
    out[i] = (1.f - z) * n + z * hprev[i];
}

__global__ __launch_bounds__(256) void k_copy(const float* __restrict__ src,
                                              float* __restrict__ dst, int n)
{
    const int i = blockIdx.x * 256 + threadIdx.x;
    if (i < n) dst[i] = src[i];
}

extern "C" void kernel_launch(void* const* d_in, const int* in_sizes, int n_in,
                              void* d_out, int out_size, void* d_ws, size_t ws_size,
                              hipStream_t stream)
{
    (void)in_sizes; (void)n_in; (void)out_size;

    const float* vertex_mask = (const float*)d_in[1];
    const int*   vertex      = (const int*)d_in[2];
    const int*   edge        = (const int*)d_in[3];
    const int*   atom_adj    = (const int*)d_in[4];
    const int*   bond_adj    = (const int*)d_in[5];
    const float* nbs_mask    = (const float*)d_in[6];
    const float* init_atom   = (const float*)d_in[7];
    const float* init_bond   = (const float*)d_in[8];
    const float* emb_w  = (const float*)d_in[9];
    const float* emb_b  = (const float*)d_in[10];
    const float* Wa_w   = (const float*)d_in[11];
    const float* Wa_b   = (const float*)d_in[12];
    const float* Wbmm_w = (const float*)d_in[13];
    const float* Wbmm_b = (const float*)d_in[14];
    const float* Wm_w   = (const float*)d_in[15];
    const float* Wm_b   = (const float*)d_in[16];
    const float* Wm2s_w = (const float*)d_in[17];
    const float* Wm2s_b = (const float*)d_in[18];
    const float* Ws2m_w = (const float*)d_in[19];
    const float* Ws2m_b = (const float*)d_in[20];
    const float* Wsup_w = (const float*)d_in[21];
    const float* Wsup_b = (const float*)d_in[22];
    const float* Wzm1_w = (const float*)d_in[23];
    const float* Wzm1_b = (const float*)d_in[24];
    const float* Wzm2_w = (const float*)d_in[25];
    const float* Wzm2_b = (const float*)d_in[26];
    const float* Wzs1_w = (const float*)d_in[27];
    const float* Wzs1_b = (const float*)d_in[28];
    const float* Wzs2_w = (const float*)d_in[29];
    const float* Wzs2_b = (const float*)d_in[30];
    const float* U2_w   = (const float*)d_in[31];
    const float* U2_b   = (const float*)d_in[32];
    const float* U1_w   = (const float*)d_in[33];
    const float* U1_b   = (const float*)d_in[34];
    const float* gm_wih = (const float*)d_in[35];
    const float* gm_whh = (const float*)d_in[36];
    const float* gm_bih = (const float*)d_in[37];
    const float* gm_bhh = (const float*)d_in[38];
    const float* gs_wih = (const float*)d_in[39];
    const float* gs_whh = (const float*)d_in[40];
    const float* gs_bih = (const float*)d_in[41];
    const float* gs_bhh = (const float*)d_in[42];

    const size_t MB = 1u << 20;
    if (ws_size < 68 * MB) return;

    char* base = (char*)d_ws;
    float*    X0   = (float*)base;                  // 16 MB fp32 vf ping
    ushort_t* Pb   = (ushort_t*)(base + 16 * MB);   // 8 MB bf16
    ushort_t* Qb   = (ushort_t*)(base + 24 * MB);   // 8 MB
    ushort_t* NEIb = (ushort_t*)(base + 32 * MB);   // 8 MB
    ushort_t* MSb  = (ushort_t*)(base + 40 * MB);   // 8 MB
    ushort_t* HIDb = (ushort_t*)(base + 48 * MB);   // 8 MB (+8 MB spare to 64 MB)
    ushort_t* giB  = Pb;                            // 24 MB overlay
    ushort_t* ghB  = MSb;                           // 24 MB overlay
    ushort_t* WT   = (ushort_t*)(base + 64 * MB);   // ~0.9 MB bf16 weights
    float*    S    = (float*)(base + 66 * MB);

    float* sfA    = S;
    float* sfB    = S + 16384;
    float* a_buf  = S + 32768;
    float* attn   = S + 98304;
    float* s2m    = S + 163840;
    float* c_zm2  = S + 180224;

    float* X1 = (float*)d_out;
    float* sf_final = X1 + (size_t)BN * Hd;

    // Wt layout (ushort offsets)
    const int PERD = 106496;
    const int OFF_EMB = 0;
    const int OFF_L0  = 16384;
    const int OFF_GIH = 16384 + 3 * PERD;
    const int OFF_GHH = OFF_GIH + 49152;

    // ---- fused prep (single launch) ----
    PrepJobs PJ;
    int nj = 0, blk0 = 0;
    auto addJob = [&](const float* W, int K, int ldw, long sStride, int nPer,
                      int Kpad, int ncols, int outOff) {
        PrepJob& J = PJ.j[nj++];
        J.W = W; J.K = K; J.ldw = ldw; J.sliceStride = sStride; J.nPerSlice = nPer;
        J.Kpad = Kpad; J.total = ncols * Kpad; J.outOff = outOff; J.blockStart = blk0;
        blk0 += (J.total + 255) / 256;
    };
    addJob(emb_w, AFd, Hd, 0, Hd, 128, 128, OFF_EMB);
    for (int d = 0; d < Dd; ++d) {
        const int o = OFF_L0 + d * PERD;
        addJob(Wa_w + (long)d * Kk * Hd * Hd, Hd, Hd, (long)Hd * Hd, Hd, 128, 256, o);
        addJob(U2_w + (long)d * (Hd + BFd) * Hd, Hd, Hd, 0, Hd, 128, 128, o + 32768);
        addJob(U2_w + (long)d * (Hd + BFd) * Hd + Hd * Hd, BFd, Hd, 0, Hd, 64, 128, o + 49152);
        addJob(U1_w + (long)d * 2 * Hd * Hd, 2 * Hd, Hd, 0, Hd, 256, 128, o + 57344);
        addJob(Wzm1_w + (long)d * Hd * Hd, Hd, Hd, 0, Hd, 128, 128, o + 90112);
    }
    addJob(gm_wih, Hd, 3 * Hd, 0, 3 * Hd, 128, 384, OFF_GIH);
    addJob(gm_whh, Hd, 3 * Hd, 0, 3 * Hd, 128, 384, OFF_GHH);
    PJ.nJobs = nj;
    k_prep_all<<<dim3(blk0), dim3(256), 0, stream>>>(PJ, WT);

    const dim3 blk(256);
    const dim3 g1(BN / 128, 1);

    // embed
    mgemm<EPI_LRELU, false, false><<<g1, blk, 0, stream>>>(
        init_atom, AFd, AFd, nullptr, 0, 0, vertex,
        WT + OFF_EMB, 128, emb_b, 0,
        X0, Hd, 0, nullptr, nullptr, 0, nullptr, nullptr);
    k_sfv<<<dim3(B), blk, 0, stream>>>(X0, vertex_mask, sfA);

    for (int d = 0; d < Dd; ++d) {
        float* vin  = (d & 1) ? X1 : X0;
        float* vout = (d & 1) ? X0 : X1;
        float* sin  = (d & 1) ? sfB : sfA;
        float* sout = (d & 1) ? sfA : sfB;

        const int o = OFF_L0 + d * PERD;
        ushort_t* wt_wa  = WT + o;
        ushort_t* wt_u2v = WT + o + 32768;
        ushort_t* wt_u2e = WT + o + 49152;
        ushort_t* wt_u1  = WT + o + 57344;
        ushort_t* wt_zm1 = WT + o + 90112;

        // a[b,k,n]: tanh GEMM + fused dot-reduce
        mgemm<EPI_TANHDOT, false, false><<<dim3(BN / 128, Kk), blk, 0, stream>>>(
            vin, Hd, Hd, nullptr, 0, 0, nullptr,
            wt_wa, 128,
            Wa_b + (long)d * Kk * Hd, Hd,
            a_buf, 0, Nv,
            sin, Wbmm_w + (long)d * Kk * Hd, Hd, Wbmm_b + (long)d * Kk, nullptr);
        k_softmax<<<dim3(B * Kk), blk, 0, stream>>>(a_buf, vertex_mask, attn);

        // fused supernode chain (t, m_vec, m2s, s2m, ss, czm2, z_super, GRU super)
        k_super<<<dim3(B), blk, 0, stream>>>(
            attn, vin, sin,
            Wm_w + (long)d * Kk * Hd * Hd, Wm_b + (long)d * Kk * Hd,
            Wm2s_w + (long)d * Kk * Hd * Hd, Wm2s_b + (long)d * Hd,
            Ws2m_w + (long)d * Hd * Hd, Ws2m_b + (long)d * Hd,
            Wsup_w + (long)d * Hd * Hd, Wsup_b + (long)d * Hd,
            Wzm2_w + (long)d * Hd * Hd, Wzm2_b + (long)d * Hd,
            Wzs1_w + (long)d * Hd * Hd, Wzs1_b + (long)d * Hd,
            Wzs2_w + (long)d * Hd * Hd, Wzs2_b + (long)d * Hd,
            gs_wih, gs_whh, gs_bih, gs_bhh,
            s2m, c_zm2, sout);

        // P = vf@U2v + b ; Q = bond_init[edge]@U2e
        mgemm<EPI_NONE, false, true><<<g1, blk, 0, stream>>>(
            vin, Hd, Hd, nullptr, 0, 0, nullptr,
            wt_u2v, 128, U2_b + (long)d * Hd, 0,
            Pb, Hd, 0, nullptr, nullptr, 0, nullptr, nullptr);
        mgemm<EPI_NONE, false, true><<<g1, blk, 0, stream>>>(
            init_bond, BFd, BFd, nullptr, 0, 0, edge,
            wt_u2e, 64, nullptr, 0,
            Qb, Hd, 0, nullptr, nullptr, 0, nullptr, nullptr);
        k_gather<<<dim3(BN / 2), blk, 0, stream>>>(Pb, Qb, atom_adj, bond_adj, nbs_mask, NEIb);

        // main_self = lrelu([vf, nei]@U1 + b)
        mgemm<EPI_LRELU, false, true><<<g1, blk, 0, stream>>>(
            vin, Hd, Hd, NEIb, Hd, Hd, nullptr,
            wt_u1, 256, U1_b + (long)d * Hd, 0,
            MSb, Hd, 0, nullptr, nullptr, 0, nullptr, nullptr);

        // hidden_main (ZMAIN fused)
        mgemm<EPI_ZMAIN, true, true><<<g1, blk, 0, stream>>>(
            MSb, Hd, Hd, nullptr, 0, 0, nullptr,
            wt_zm1, 128, Wzm1_b + (long)d * Hd, 0,
            HIDb, Hd, 0,
            c_zm2, nullptr, 0, s2m, MSb);

        // GRU main
        mgemm<EPI_NONE, true, true><<<dim3(BN / 128, 3), blk, 0, stream>>>(
            HIDb, Hd, Hd, nullptr, 0, 0, nullptr,
            WT + OFF_GIH, 128, gm_bih, 128,
            giB, 3 * Hd, 128, nullptr, nullptr, 0, nullptr, nullptr);
        mgemm<EPI_NONE, false, true><<<dim3(BN / 128, 3), blk, 0, stream>>>(
            vin, Hd, Hd, nullptr, 0, 0, nullptr,
            WT + OFF_GHH, 128, gm_bhh, 128,
            ghB, 3 * Hd, 128, nullptr, nullptr, 0, nullptr, nullptr);
        k_comb<<<dim3(BN * Hd / 256), blk, 0, stream>>>(giB, ghB, vin, vout);
    }

    k_copy<<<dim3((B * Hd + 255) / 256), blk, 0, stream>>>(sfB, sf_final, B * Hd);
}

// Round 4
// 432.646 us; speedup vs baseline: 3.2999x; 1.5289x over previous
//
#include <hip/hip_runtime.h>

typedef unsigned short ushort_t;
typedef unsigned int uint_t;
typedef __attribute__((ext_vector_type(8))) short short8;
typedef __attribute__((ext_vector_type(4))) float f32x4;

#define B   128
#define Nv  256
#define Mn  12
#define Hd  128
#define Dd  3
#define Kk  2
#define AFd 82
#define BFd 6
#define BN  (B*Nv)   // 32768

enum { EPI_NONE = 0, EPI_LRELU = 1, EPI_TANHDOT = 2, EPI_ZMAIN = 3 };

__device__ __forceinline__ float lrelu(float x) { return x > 0.f ? x : 0.1f * x; }
__device__ __forceinline__ float sigmoidf(float x) { return 1.f / (1.f + expf(-x)); }
__device__ __forceinline__ ushort_t f2b(float x) {
    uint_t u = __float_as_uint(x);
    return (ushort_t)((u + 0x7FFFu + ((u >> 16) & 1u)) >> 16);
}
__device__ __forceinline__ float b2f(ushort_t s) {
    return __uint_as_float(((uint_t)s) << 16);
}
__device__ __forceinline__ void b2f4(uint2 u, float* o) {
    o[0] = __uint_as_float((u.x & 0xFFFFu) << 16);
    o[1] = __uint_as_float(u.x & 0xFFFF0000u);
    o[2] = __uint_as_float((u.y & 0xFFFFu) << 16);
    o[3] = __uint_as_float(u.y & 0xFFFF0000u);
}

// ---------------- fused weight prep (one launch) ----------------
struct PrepJob {
    const float* W;
    long sliceStride;
    int K, ldw, nPerSlice, Kspan, KpadRow, kDst, total, outOff, blockStart;
};
struct PrepJobs { PrepJob j[18]; int nJobs; };

__global__ __launch_bounds__(256) void k_prep_all(PrepJobs P, ushort_t* __restrict__ WT)
{
    int bid = blockIdx.x;
    int ji = 0;
    #pragma unroll 1
    while (ji + 1 < P.nJobs && P.j[ji + 1].blockStart <= bid) ++ji;
    const PrepJob J = P.j[ji];
    const int idx = (bid - J.blockStart) * 256 + threadIdx.x;
    if (idx >= J.total) return;
    const int n = idx / J.Kspan, k = idx % J.Kspan;
    const int slice = n / J.nPerSlice, nn = n % J.nPerSlice;
    float v = (k < J.K) ? J.W[(size_t)slice * J.sliceStride + (size_t)k * J.ldw + nn] : 0.f;
    WT[(size_t)J.outOff + (size_t)n * J.KpadRow + J.kDst + k] = f2b(v);
}

// qtab[d][j][h] = sum_f init_bond[j,f] * U2_w[d][128+f][h]   (12 rows per layer)
__global__ __launch_bounds__(256) void k_qtab(const float* __restrict__ init_bond,
                                              const float* __restrict__ U2w,
                                              float* __restrict__ qt)
{
    const int d = blockIdx.x;
    const float* W = U2w + (size_t)d * (Hd + BFd) * Hd + (size_t)Hd * Hd;
    float* q = qt + (size_t)d * 12 * Hd;
    for (int idx = threadIdx.x; idx < 12 * Hd; idx += 256) {
        const int j = idx >> 7, h = idx & 127;
        float s = 0.f;
        #pragma unroll
        for (int f = 0; f < BFd; ++f) s += init_bond[j * BFd + f] * W[f * Hd + h];
        q[idx] = s;
    }
}

// ---------------- bf16 MFMA GEMM (64x128 tile, 4 waves, 2 blocks/CU) ----------------
template<int EPI, bool ABF, bool OBF>
__global__ __launch_bounds__(256) void mgemm(
    const void* __restrict__ A1v, const void* __restrict__ A1alt, int altY,
    int lda1, int K1,
    const ushort_t* __restrict__ A2, int lda2, int K2,
    const int* __restrict__ rowidx,
    const ushort_t* __restrict__ Wt, int Kpad,
    const float* __restrict__ b1, const float* __restrict__ b1alt,
    const float* __restrict__ b2, long b1sY,
    void* __restrict__ outv, long ldo, long oY,
    const float* __restrict__ e0,
    const float* __restrict__ e1, long e1sY,
    const float* __restrict__ e2,
    const ushort_t* __restrict__ eMS)
{
    const int t    = threadIdx.x;
    const int lane = t & 63;
    const int w    = t >> 6;
    const int wm   = w >> 1, wn = w & 1;
    const int lr   = lane & 15, lg = lane >> 4;
    const int row0 = blockIdx.x * 64;
    const int ky   = blockIdx.y;
    int kyb = ky;
    if (A1alt != nullptr && ky >= altY) { A1v = A1alt; b1 = b1alt; kyb = ky - altY; }
    const int Ktot = K1 + K2;

    __shared__ ushort_t As[64 * 64];
    __shared__ ushort_t Bs[128 * 64];
    __shared__ float EUs[128];
    __shared__ float EBb[128];
    __shared__ float red[64][2];

    const ushort_t* Wty = Wt + (size_t)ky * 128 * Kpad;

    f32x4 acc[2][4];
    #pragma unroll
    for (int i = 0; i < 2; ++i)
        #pragma unroll
        for (int j = 0; j < 4; ++j)
            acc[i][j] = (f32x4){0.f, 0.f, 0.f, 0.f};

    const int r_st = t >> 2, q4 = t & 3;       // A staging: row, k-quarter (16 k's)
    const int c_st = t >> 1, half = t & 1;     // B staging: col, k-half (32 k's)
    const int grow = row0 + r_st;
    const long arow = rowidx ? (long)rowidx[grow] : (long)grow;

    const int nck = Kpad >> 6;
    for (int ck = 0; ck < nck; ++ck) {
        if (ck) __syncthreads();
        // ---- stage A (16 k's per thread) ----
        {
            const int kb = ck * 64 + q4 * 16;
            union { ushort_t us[16]; uint4 qv[2]; } tmp;
            const bool al1 = ABF ? ((lda1 & 7) == 0) : ((lda1 & 3) == 0);
            const bool fast1 = al1 && (kb + 16 <= K1);
            const bool fast2 = (A2 != nullptr) && (kb >= K1) && (kb + 16 <= Ktot);
            if (ABF && fast1) {
                const ushort_t* src = (const ushort_t*)A1v + (size_t)arow * lda1 + kb;
                tmp.qv[0] = ((const uint4*)src)[0];
                tmp.qv[1] = ((const uint4*)src)[1];
            } else if (!ABF && fast1) {
                const float* src = (const float*)A1v + (size_t)arow * lda1 + kb;
                #pragma unroll
                for (int v2 = 0; v2 < 4; ++v2) {
                    float4 f = ((const float4*)src)[v2];
                    tmp.us[v2*4+0] = f2b(f.x); tmp.us[v2*4+1] = f2b(f.y);
                    tmp.us[v2*4+2] = f2b(f.z); tmp.us[v2*4+3] = f2b(f.w);
                }
            } else if (fast2) {
                const ushort_t* src = A2 + (size_t)grow * lda2 + (kb - K1);
                tmp.qv[0] = ((const uint4*)src)[0];
                tmp.qv[1] = ((const uint4*)src)[1];
            } else {
                #pragma unroll
                for (int j = 0; j < 16; ++j) {
                    const int kg = kb + j;
                    ushort_t v = 0;
                    if (kg < K1) {
                        if (ABF) v = ((const ushort_t*)A1v)[(size_t)arow * lda1 + kg];
                        else     v = f2b(((const float*)A1v)[(size_t)arow * lda1 + kg]);
                    } else if (kg < Ktot) {
                        v = A2[(size_t)grow * lda2 + (kg - K1)];
                    }
                    tmp.us[j] = v;
                }
            }
            #pragma unroll
            for (int j = 0; j < 2; ++j) {
                int byte = r_st * 128 + q4 * 32 + j * 16;
                byte ^= ((r_st & 7) << 4);
                *(uint4*)((char*)As + byte) = tmp.qv[j];
            }
        }
        // ---- stage B (32 k's per thread) ----
        {
            const ushort_t* src = Wty + (size_t)c_st * Kpad + ck * 64 + half * 32;
            #pragma unroll
            for (int v2 = 0; v2 < 4; ++v2) {
                uint4 wv = ((const uint4*)src)[v2];
                int byte = c_st * 128 + half * 64 + v2 * 16;
                byte ^= ((c_st & 7) << 4);
                *(uint4*)((char*)Bs + byte) = wv;
            }
        }
        __syncthreads();
        // ---- MFMA ----
        #pragma unroll
        for (int ks = 0; ks < 64; ks += 32) {
            short8 af[2], bfr[4];
            #pragma unroll
            for (int mf = 0; mf < 2; ++mf) {
                const int row = wm * 32 + mf * 16 + lr;
                int byte = row * 128 + (ks + lg * 8) * 2;
                byte ^= ((row & 7) << 4);
                af[mf] = *(const short8*)((const char*)As + byte);
            }
            #pragma unroll
            for (int nf = 0; nf < 4; ++nf) {
                const int col = wn * 64 + nf * 16 + lr;
                int byte = col * 128 + (ks + lg * 8) * 2;
                byte ^= ((col & 7) << 4);
                bfr[nf] = *(const short8*)((const char*)Bs + byte);
            }
            #pragma unroll
            for (int mf = 0; mf < 2; ++mf)
                #pragma unroll
                for (int nf = 0; nf < 4; ++nf)
                    acc[mf][nf] = __builtin_amdgcn_mfma_f32_16x16x32_bf16(
                        af[mf], bfr[nf], acc[mf][nf], 0, 0, 0);
        }
    }

    // ---- epilogue ----
    if constexpr (EPI == EPI_TANHDOT) {
        __syncthreads();
        if (t < 128) {
            const int b = row0 >> 8;
            EUs[t] = e0[b * Hd + t] * e1[(size_t)ky * e1sY + t];
            EBb[t] = b1[(size_t)kyb * b1sY + t];
        }
        __syncthreads();
        #pragma unroll
        for (int mf = 0; mf < 2; ++mf) {
            #pragma unroll
            for (int reg = 0; reg < 4; ++reg) {
                float p = 0.f;
                #pragma unroll
                for (int nf = 0; nf < 4; ++nf) {
                    const int c = wn * 64 + nf * 16 + lr;
                    p += tanhf(acc[mf][nf][reg] + EBb[c]) * EUs[c];
                }
                p += __shfl_xor(p, 1); p += __shfl_xor(p, 2);
                p += __shfl_xor(p, 4); p += __shfl_xor(p, 8);
                if (lr == 0) red[wm * 32 + mf * 16 + lg * 4 + reg][wn] = p;
            }
        }
        __syncthreads();
        if (t < 64) {
            const int gr = row0 + t;
            const float a = red[t][0] + red[t][1] + e2[ky];
            ((float*)outv)[(size_t)(gr >> 8) * (Kk * Nv) + (size_t)ky * oY + (gr & 255)] = a;
        }
    } else {
        const int b = row0 >> 8;
        #pragma unroll
        for (int mf = 0; mf < 2; ++mf) {
            #pragma unroll
            for (int nf = 0; nf < 4; ++nf) {
                const int c = wn * 64 + nf * 16 + lr;
                #pragma unroll
                for (int reg = 0; reg < 4; ++reg) {
                    const int r = wm * 32 + mf * 16 + lg * 4 + reg;
                    const size_t row = (size_t)row0 + r;
                    float v = acc[mf][nf][reg];
                    if (b1) v += b1[(size_t)kyb * b1sY + c];
                    if (b2) v += b2[(size_t)kyb * b1sY + c];
                    if constexpr (EPI == EPI_LRELU) v = lrelu(v);
                    if constexpr (EPI == EPI_ZMAIN) {
                        const float z = sigmoidf(v + e0[b * Hd + c]);
                        const float ms = b2f(eMS[row * Hd + c]);
                        v = (1.f - z) * ms + z * e2[b * Hd + c];
                    }
                    const size_t oidx = row * ldo + (size_t)ky * oY + c;
                    if (OBF) ((ushort_t*)outv)[oidx] = f2b(v);
                    else     ((float*)outv)[oidx] = v;
                }
            }
        }
    }
}

// ---------------- GEMV building block (fp32 weights) ----------------
__device__ __forceinline__ void gemv128(const float* __restrict__ W, int ldw, int off,
                                        const float* __restrict__ x, int K,
                                        float (*red)[32][4], float* __restrict__ y, int t)
{
    const int gq = t & 31, hs = t >> 5;
    const int hn = K >> 3;
    f32x4 acc = (f32x4){0.f, 0.f, 0.f, 0.f};
    const float* Wp = W + (size_t)off + (size_t)gq * 4;
    const int h0 = hs * hn;
    #pragma unroll 8
    for (int i = 0; i < hn; ++i) {
        const float4 wv = *(const float4*)&Wp[(size_t)(h0 + i) * ldw];
        const float xv = x[h0 + i];
        acc.x = fmaf(xv, wv.x, acc.x);
        acc.y = fmaf(xv, wv.y, acc.y);
        acc.z = fmaf(xv, wv.z, acc.z);
        acc.w = fmaf(xv, wv.w, acc.w);
    }
    *(f32x4*)&red[hs][gq][0] = acc;
    __syncthreads();
    if (t < 128) {
        float s = 0.f;
        #pragma unroll
        for (int p = 0; p < 8; ++p) s += red[p][t >> 2][t & 3];
        y[t] = s;
    }
    __syncthreads();
}

// ---------------- fused softmax + supernode chain, one block per b ----------------
__global__ __launch_bounds__(256) void k_super(
    const float* __restrict__ a_buf, const float* __restrict__ vmask,
    const ushort_t* __restrict__ vfb,
    const float* __restrict__ sf_in,
    const float* __restrict__ Wm, const float* __restrict__ bm,
    const float* __restrict__ Wm2s, const float* __restrict__ bm2s,
    const float* __restrict__ Ws2m, const float* __restrict__ bs2m,
    const float* __restrict__ Wsup, const float* __restrict__ bsup,
    const float* __restrict__ Wzm2, const float* __restrict__ bzm2,
    const float* __restrict__ Wzs1, const float* __restrict__ bzs1,
    const float* __restrict__ Wzs2, const float* __restrict__ bzs2,
    const float* __restrict__ gwih, const float* __restrict__ gwhh,
    const float* __restrict__ gbih, const float* __restrict__ gbhh,
    float* __restrict__ s2m_g, float* __restrict__ czm2_g,
    float* __restrict__ sf_out)
{
    const int b = blockIdx.x, t = threadIdx.x;
    const int wid = t >> 6, lane = t & 63;
    __shared__ float red[8][32][4];
    __shared__ float att0[256], att1[256];
    __shared__ float sfl[128], tbA[128], tbB[128], mv[256];
    __shared__ float ms2[128], s2ml[128], ssl[128], hsl[128], tmp1[128], tmp2[128];
    __shared__ float gib[384], ghb[384];
    __shared__ float saS[2];
    __shared__ float lm[4][2], ls[4][2];

    // ---- masked softmax for k=0,1 (fused) ----
    const float v0 = a_buf[(size_t)b * 512 + t];
    const float v1 = a_buf[(size_t)b * 512 + 256 + t];
    const float vm = vmask[b * Nv + t];
    float m0 = v0, m1 = v1;
    #pragma unroll
    for (int o = 1; o < 64; o <<= 1) {
        m0 = fmaxf(m0, __shfl_xor(m0, o));
        m1 = fmaxf(m1, __shfl_xor(m1, o));
    }
    if (lane == 0) { lm[wid][0] = m0; lm[wid][1] = m1; }
    __syncthreads();
    m0 = fmaxf(fmaxf(lm[0][0], lm[1][0]), fmaxf(lm[2][0], lm[3][0]));
    m1 = fmaxf(fmaxf(lm[0][1], lm[1][1]), fmaxf(lm[2][1], lm[3][1]));
    const float e0v = expf(v0 - m0) * vm;
    const float e1v = expf(v1 - m1) * vm;
    float s0 = e0v, s1 = e1v;
    #pragma unroll
    for (int o = 1; o < 64; o <<= 1) {
        s0 += __shfl_xor(s0, o);
        s1 += __shfl_xor(s1, o);
    }
    if (lane == 0) { ls[wid][0] = s0; ls[wid][1] = s1; }
    if (t < 128) sfl[t] = sf_in[b * Hd + t];
    __syncthreads();
    s0 = ls[0][0] + ls[1][0] + ls[2][0] + ls[3][0];
    s1 = ls[0][1] + ls[1][1] + ls[2][1] + ls[3][1];
    att0[t] = e0v / (s0 + 1e-6f);
    att1[t] = e1v / (s1 + 1e-6f);
    if (t == 0) { saS[0] = s0 / (s0 + 1e-6f); saS[1] = s1 / (s1 + 1e-6f); }
    __syncthreads();

    // ---- t[k,h] = sum_n attn[k,n] * vf[b,n,h]  (bf16 vf) ----
    {
        const int hq = t & 31, ns = t >> 5;
        f32x4 a0 = (f32x4){0.f,0.f,0.f,0.f}, a1 = (f32x4){0.f,0.f,0.f,0.f};
        const ushort_t* base = vfb + (size_t)b * Nv * Hd + hq * 4;
        #pragma unroll 8
        for (int i = 0; i < 32; ++i) {
            const int n = ns * 32 + i;
            float xv[4];
            b2f4(*(const uint2*)&base[(size_t)n * Hd], xv);
            const float w0 = att0[n], w1 = att1[n];
            a0.x = fmaf(w0, xv[0], a0.x); a0.y = fmaf(w0, xv[1], a0.y);
            a0.z = fmaf(w0, xv[2], a0.z); a0.w = fmaf(w0, xv[3], a0.w);
            a1.x = fmaf(w1, xv[0], a1.x); a1.y = fmaf(w1, xv[1], a1.y);
            a1.z = fmaf(w1, xv[2], a1.z); a1.w = fmaf(w1, xv[3], a1.w);
        }
        *(f32x4*)&red[ns][hq][0] = a0;
        __syncthreads();
        if (t < 128) { float s = 0.f;
            #pragma unroll
            for (int p = 0; p < 8; ++p) s += red[p][t >> 2][t & 3];
            tbA[t] = s; }
        __syncthreads();
        *(f32x4*)&red[ns][hq][0] = a1;
        __syncthreads();
        if (t < 128) { float s = 0.f;
            #pragma unroll
            for (int p = 0; p < 8; ++p) s += red[p][t >> 2][t & 3];
            tbB[t] = s; }
        __syncthreads();
    }

    // m_vec
    gemv128(Wm, Hd, 0, tbA, Hd, red, mv, t);
    gemv128(Wm + Hd * Hd, Hd, 0, tbB, Hd, red, mv + 128, t);
    mv[t] += saS[t >> 7] * bm[t];
    __syncthreads();

    // m2s = tanh(m_vec @ Wm2s + b)
    gemv128(Wm2s, Hd, 0, mv, 2 * Hd, red, tmp1, t);
    if (t < 128) ms2[t] = tanhf(tmp1[t] + bm2s[t]);
    __syncthreads();

    // s2m, ss
    gemv128(Ws2m, Hd, 0, sfl, Hd, red, tmp1, t);
    if (t < 128) { const float v = tanhf(tmp1[t] + bs2m[t]); s2ml[t] = v; s2m_g[b * Hd + t] = v; }
    __syncthreads();
    gemv128(Wsup, Hd, 0, sfl, Hd, red, tmp1, t);
    if (t < 128) ssl[t] = tanhf(tmp1[t] + bsup[t]);
    __syncthreads();

    // c_zm2 export
    gemv128(Wzm2, Hd, 0, s2ml, Hd, red, tmp1, t);
    if (t < 128) czm2_g[b * Hd + t] = tmp1[t] + bzm2[t];

    // z_super, hidden_super
    gemv128(Wzs1, Hd, 0, ssl, Hd, red, tmp1, t);
    gemv128(Wzs2, Hd, 0, ms2, Hd, red, tmp2, t);
    if (t < 128) {
        const float zs = sigmoidf(tmp1[t] + bzs1[t] + tmp2[t] + bzs2[t]);
        hsl[t] = (1.f - zs) * ssl[t] + zs * ms2[t];
    }
    __syncthreads();

    // super GRU
    #pragma unroll 1
    for (int c = 0; c < 3; ++c) {
        gemv128(gwih, 3 * Hd, c * Hd, hsl, Hd, red, tmp1, t);
        if (t < 128) gib[c * Hd + t] = tmp1[t] + gbih[c * Hd + t];
        gemv128(gwhh, 3 * Hd, c * Hd, sfl, Hd, red, tmp2, t);
        if (t < 128) ghb[c * Hd + t] = tmp2[t] + gbhh[c * Hd + t];
    }
    __syncthreads();
    if (t < 128) {
        const float r = sigmoidf(gib[t] + ghb[t]);
        const float z = sigmoidf(gib[128 + t] + ghb[128 + t]);
        const float n = tanhf(gib[256 + t] + r * ghb[256 + t]);
        sf_out[b * Hd + t] = (1.f - z) * n + z * sfl[t];
    }
}

// sf[b,h] = sum_n vf[b,n,h]*vmask[b,n]  (bf16 vf)
__global__ __launch_bounds__(256) void k_sfv(const ushort_t* __restrict__ vfb,
                                             const float* __restrict__ vmask,
                                             float* __restrict__ sf)
{
    const int b = blockIdx.x, t = threadIdx.x;
    __shared__ float vm[256];
    __shared__ float red[8][32][4];
    vm[t] = vmask[b * Nv + t];
    __syncthreads();
    const int hq = t & 31, ns = t >> 5;
    f32x4 acc = (f32x4){0.f,0.f,0.f,0.f};
    const ushort_t* base = vfb + (size_t)b * Nv * Hd + hq * 4;
    #pragma unroll 8
    for (int i = 0; i < 32; ++i) {
        const int n = ns * 32 + i;
        float xv[4];
        b2f4(*(const uint2*)&base[(size_t)n * Hd], xv);
        const float w = vm[n];
        acc.x = fmaf(w, xv[0], acc.x); acc.y = fmaf(w, xv[1], acc.y);
        acc.z = fmaf(w, xv[2], acc.z); acc.w = fmaf(w, xv[3], acc.w);
    }
    *(f32x4*)&red[ns][hq][0] = acc;
    __syncthreads();
    if (t < 128) {
        float s = 0.f;
        #pragma unroll
        for (int p = 0; p < 8; ++p) s += red[p][t >> 2][t & 3];
        sf[b * Hd + t] = s;
    }
}

// nei_label via P-gather + 12-row Q table
__global__ __launch_bounds__(256) void k_gather(const ushort_t* __restrict__ P,
                                                const float* __restrict__ qtab,
                                                const int* __restrict__ aadj,
                                                const int* __restrict__ badj,
                                                const int* __restrict__ edge,
                                                const float* __restrict__ nmask,
                                                ushort_t* __restrict__ nei)
{
    const int sub = threadIdx.x >> 7;
    const int bn = blockIdx.x * 2 + sub;
    const int h = threadIdx.x & 127;
    __shared__ int ai[2][Mn];
    __shared__ int ei[2][Mn];
    __shared__ float mk[2][Mn];
    if (h < Mn) {
        ai[sub][h] = aadj[(long)bn * Mn + h];
        ei[sub][h] = edge[badj[(long)bn * Mn + h]];
        mk[sub][h] = nmask[(long)bn * Mn + h];
    }
    __syncthreads();
    float acc = 0.f;
    #pragma unroll
    for (int m = 0; m < Mn; ++m) {
        const float v = b2f(P[(size_t)ai[sub][m] * Hd + h]) + qtab[ei[sub][m] * Hd + h];
        acc += mk[sub][m] * lrelu(v);
    }
    nei[(size_t)bn * Hd + h] = f2b(acc);
}

// GRU combine from RZ[row][256] and NH[row][256] (bf16)
template<bool OBF>
__global__ __launch_bounds__(256) void k_comb(const ushort_t* __restrict__ rz,
                                              const ushort_t* __restrict__ nh,
                                              const ushort_t* __restrict__ hprev,
                                              void* __restrict__ out)
{
    const long i = (long)blockIdx.x * 256 + threadIdx.x;
    const long row = i >> 7;
    const int c = (int)(i & 127);
    const size_t bb = (size_t)row * 256 + c;
    const float r = sigmoidf(b2f(rz[bb]));
    const float z = sigmoidf(b2f(rz[bb + 128]));
    const float n = tanhf(b2f(nh[bb]) + r * b2f(nh[bb + 128]));
    const float h = b2f(hprev[i]);
    const float o = (1.f - z) * n + z * h;
    if (OBF) ((ushort_t*)out)[i] = f2b(o);
    else     ((float*)out)[i] = o;
}

__global__ __launch_bounds__(256) void k_copy(const float* __restrict__ src,
                                              float* __restrict__ dst, int n)
{
    const int i = blockIdx.x * 256 + threadIdx.x;
    if (i < n) dst[i] = src[i];
}

extern "C" void kernel_launch(void* const* d_in, const int* in_sizes, int n_in,
                              void* d_out, int out_size, void* d_ws, size_t ws_size,
                              hipStream_t stream)
{
    (void)in_sizes; (void)n_in; (void)out_size;

    const float* vertex_mask = (const float*)d_in[1];
    const int*   vertex      = (const int*)d_in[2];
    const int*   edge        = (const int*)d_in[3];
    const int*   atom_adj    = (const int*)d_in[4];
    const int*   bond_adj    = (const int*)d_in[5];
    const float* nbs_mask    = (const float*)d_in[6];
    const float* init_atom   = (const float*)d_in[7];
    const float* init_bond   = (const float*)d_in[8];
    const float* emb_w  = (const float*)d_in[9];
    const float* emb_b  = (const float*)d_in[10];
    const float* Wa_w   = (const float*)d_in[11];
    const float* Wa_b   = (const float*)d_in[12];
    const float* Wbmm_w = (const float*)d_in[13];
    const float* Wbmm_b = (const float*)d_in[14];
    const float* Wm_w   = (const float*)d_in[15];
    const float* Wm_b   = (const float*)d_in[16];
    const float* Wm2s_w = (const float*)d_in[17];
    const float* Wm2s_b = (const float*)d_in[18];
    const float* Ws2m_w = (const float*)d_in[19];
    const float* Ws2m_b = (const float*)d_in[20];
    const float* Wsup_w = (const float*)d_in[21];
    const float* Wsup_b = (const float*)d_in[22];
    const float* Wzm1_w = (const float*)d_in[23];
    const float* Wzm1_b = (const float*)d_in[24];
    const float* Wzm2_w = (const float*)d_in[25];
    const float* Wzm2_b = (const float*)d_in[26];
    const float* Wzs1_w = (const float*)d_in[27];
    const float* Wzs1_b = (const float*)d_in[28];
    const float* Wzs2_w = (const float*)d_in[29];
    const float* Wzs2_b = (const float*)d_in[30];
    const float* U2_w   = (const float*)d_in[31];
    const float* U2_b   = (const float*)d_in[32];
    const float* U1_w   = (const float*)d_in[33];
    const float* U1_b   = (const float*)d_in[34];
    const float* gm_wih = (const float*)d_in[35];
    const float* gm_whh = (const float*)d_in[36];
    const float* gm_bih = (const float*)d_in[37];
    const float* gm_bhh = (const float*)d_in[38];
    const float* gs_wih = (const float*)d_in[39];
    const float* gs_whh = (const float*)d_in[40];
    const float* gs_bih = (const float*)d_in[41];
    const float* gs_bhh = (const float*)d_in[42];

    const size_t MB = 1u << 20;
    if (ws_size < 68 * MB) return;

    char* base = (char*)d_ws;
    ushort_t* VF0  = (ushort_t*)base;               // 8 MB
    ushort_t* VF1  = (ushort_t*)(base + 8 * MB);    // 8 MB
    ushort_t* Pb   = (ushort_t*)(base + 16 * MB);   // 8 MB (dead after gather)
    ushort_t* NEIb = (ushort_t*)(base + 24 * MB);   // 8 MB (dead after U1)
    ushort_t* MSb  = (ushort_t*)(base + 32 * MB);   // 8 MB (dead after ZMAIN)
    ushort_t* HIDb = (ushort_t*)(base + 40 * MB);   // 8 MB
    ushort_t* RZb  = (ushort_t*)(base + 16 * MB);   // 16 MB overlay (Pb+NEIb dead)
    ushort_t* NHb  = (ushort_t*)(base + 48 * MB);   // 16 MB
    ushort_t* WT   = (ushort_t*)(base + 64 * MB);   // ~0.82 MB
    float*    QT   = (float*)(base + 65 * MB);      // 3*12*128 fp32
    float*    S    = (float*)(base + 66 * MB);      // small fp32

    float* sfA    = S;
    float* sfB    = S + 16384;
    float* a_buf  = S + 32768;
    float* s2m    = S + 98304;
    float* c_zm2  = S + 114688;

    float* X1 = (float*)d_out;
    float* sf_final = X1 + (size_t)BN * Hd;

    // WT layout (ushort offsets)
    const int OFF_EMB = 0;                         // 128 cols x 128
    const int PERD = 98304;                        // wa(32768)+u2v(16384)+u1(32768)+zm1(16384)
    const int OFF_L0 = 16384;
    const int OFF_RZ = OFF_L0 + 3 * PERD;          // 256 cols x Kpad 256
    const int OFF_NH = OFF_RZ + 65536;             // 256 cols x Kpad 128

    // ---- fused prep ----
    PrepJobs PJ;
    int nj = 0, blk0 = 0;
    auto addJob = [&](const float* W, int K, int ldw, long sStride, int nPer,
                      int Kspan, int KpadRow, int kDst, int ncols, int outOff) {
        PrepJob& J = PJ.j[nj++];
        J.W = W; J.K = K; J.ldw = ldw; J.sliceStride = sStride; J.nPerSlice = nPer;
        J.Kspan = Kspan; J.KpadRow = KpadRow; J.kDst = kDst;
        J.total = ncols * Kspan; J.outOff = outOff; J.blockStart = blk0;
        blk0 += (J.total + 255) / 256;
    };
    addJob(emb_w, AFd, Hd, 0, Hd, 128, 128, 0, 128, OFF_EMB);
    for (int d = 0; d < Dd; ++d) {
        const int o = OFF_L0 + d * PERD;
        addJob(Wa_w + (long)d * Kk * Hd * Hd, Hd, Hd, (long)Hd * Hd, Hd, 128, 128, 0, 256, o);
        addJob(U2_w + (long)d * (Hd + BFd) * Hd, Hd, Hd, 0, Hd, 128, 128, 0, 128, o + 32768);
        addJob(U1_w + (long)d * 2 * Hd * Hd, 2 * Hd, Hd, 0, Hd, 256, 256, 0, 128, o + 49152);
        addJob(Wzm1_w + (long)d * Hd * Hd, Hd, Hd, 0, Hd, 128, 128, 0, 128, o + 81920);
    }
    // RZ: cols 0..255 (r,z); k<128 from wih, k>=128 from whh
    addJob(gm_wih, Hd, 3 * Hd, 0, 256, 128, 256, 0,   256, OFF_RZ);
    addJob(gm_whh, Hd, 3 * Hd, 0, 256, 128, 256, 128, 256, OFF_RZ);
    // NH: cols 0..127 = inn (wih cols 256..), cols 128..255 = hn (whh cols 256..)
    addJob(gm_wih + 256, Hd, 3 * Hd, 0, 128, 128, 128, 0, 128, OFF_NH);
    addJob(gm_whh + 256, Hd, 3 * Hd, 0, 128, 128, 128, 0, 128, OFF_NH + 16384);
    PJ.nJobs = nj;
    k_prep_all<<<dim3(blk0), dim3(256), 0, stream>>>(PJ, WT);
    k_qtab<<<dim3(Dd), dim3(256), 0, stream>>>(init_bond, U2_w, QT);

    const dim3 blk(256);
    const dim3 g1(BN / 64, 1);

    // embed -> VF0 (bf16)
    mgemm<EPI_LRELU, false, true><<<g1, blk, 0, stream>>>(
        init_atom, nullptr, 0, AFd, AFd, nullptr, 0, 0, vertex,
        WT + OFF_EMB, 128, emb_b, nullptr, nullptr, 0,
        VF0, Hd, 0, nullptr, nullptr, 0, nullptr, nullptr);
    k_sfv<<<dim3(B), blk, 0, stream>>>(VF0, vertex_mask, sfA);

    for (int d = 0; d < Dd; ++d) {
        ushort_t* vin  = (d & 1) ? VF1 : VF0;
        ushort_t* vout = (d & 1) ? VF0 : VF1;
        float* sin  = (d & 1) ? sfB : sfA;
        float* sout = (d & 1) ? sfA : sfB;

        const int o = OFF_L0 + d * PERD;

        // a[b,k,n]: tanh GEMM + fused dot-reduce
        mgemm<EPI_TANHDOT, true, false><<<dim3(BN / 64, Kk), blk, 0, stream>>>(
            vin, nullptr, 0, Hd, Hd, nullptr, 0, 0, nullptr,
            WT + o, 128,
            Wa_b + (long)d * Kk * Hd, nullptr, nullptr, Hd,
            a_buf, 0, Nv,
            sin, Wbmm_w + (long)d * Kk * Hd, Hd, Wbmm_b + (long)d * Kk, nullptr);

        // fused softmax + supernode chain
        k_super<<<dim3(B), blk, 0, stream>>>(
            a_buf, vertex_mask, vin, sin,
            Wm_w + (long)d * Kk * Hd * Hd, Wm_b + (long)d * Kk * Hd,
            Wm2s_w + (long)d * Kk * Hd * Hd, Wm2s_b + (long)d * Hd,
            Ws2m_w + (long)d * Hd * Hd, Ws2m_b + (long)d * Hd,
            Wsup_w + (long)d * Hd * Hd, Wsup_b + (long)d * Hd,
            Wzm2_w + (long)d * Hd * Hd, Wzm2_b + (long)d * Hd,
            Wzs1_w + (long)d * Hd * Hd, Wzs1_b + (long)d * Hd,
            Wzs2_w + (long)d * Hd * Hd, Wzs2_b + (long)d * Hd,
            gs_wih, gs_whh, gs_bih, gs_bhh,
            s2m, c_zm2, sout);

        // P = vf@U2v + b
        mgemm<EPI_NONE, true, true><<<g1, blk, 0, stream>>>(
            vin, nullptr, 0, Hd, Hd, nullptr, 0, 0, nullptr,
            WT + o + 32768, 128, U2_b + (long)d * Hd, nullptr, nullptr, 0,
            Pb, Hd, 0, nullptr, nullptr, 0, nullptr, nullptr);
        k_gather<<<dim3(BN / 2), blk, 0, stream>>>(Pb, QT + (size_t)d * 12 * Hd,
            atom_adj, bond_adj, edge, nbs_mask, NEIb);

        // main_self = lrelu([vf, nei]@U1 + b)
        mgemm<EPI_LRELU, true, true><<<g1, blk, 0, stream>>>(
            vin, nullptr, 0, Hd, Hd, NEIb, Hd, Hd, nullptr,
            WT + o + 49152, 256, U1_b + (long)d * Hd, nullptr, nullptr, 0,
            MSb, Hd, 0, nullptr, nullptr, 0, nullptr, nullptr);

        // hidden_main (ZMAIN fused)
        mgemm<EPI_ZMAIN, true, true><<<g1, blk, 0, stream>>>(
            MSb, nullptr, 0, Hd, Hd, nullptr, 0, 0, nullptr,
            WT + o + 81920, 128, Wzm1_b + (long)d * Hd, nullptr, nullptr, 0,
            HIDb, Hd, 0,
            c_zm2, nullptr, 0, s2m, MSb);

        // RZ = [HID|vf] @ [wih;whh](rz cols) + bih + bhh
        mgemm<EPI_NONE, true, true><<<dim3(BN / 64, 2), blk, 0, stream>>>(
            HIDb, nullptr, 0, Hd, Hd, vin, Hd, Hd, nullptr,
            WT + OFF_RZ, 256, gm_bih, nullptr, gm_bhh, 128,
            RZb, 256, 128, nullptr, nullptr, 0, nullptr, nullptr);

        // NH: inn = HID@wih_n + bih_n ; hn = vf@whh_n + bhh_n
        mgemm<EPI_NONE, true, true><<<dim3(BN / 64, 2), blk, 0, stream>>>(
            HIDb, vin, 1, Hd, Hd, nullptr, 0, 0, nullptr,
            WT + OFF_NH, 128, gm_bih + 256, gm_bhh + 256, nullptr, 0,
            NHb, 256, 128, nullptr, nullptr, 0, nullptr, nullptr);

        // combine
        if (d == Dd - 1)
            k_comb<false><<<dim3(BN * Hd / 256), blk, 0, stream>>>(RZb, NHb, vin, X1);
        else
            k_comb<true><<<dim3(BN * Hd / 256), blk, 0, stream>>>(RZb, NHb, vin, vout);
    }

    k_copy<<<dim3((B * Hd + 255) / 256), blk, 0, stream>>>(sfB, sf_final, B * Hd);
}

// Round 5
// 378.417 us; speedup vs baseline: 3.7728x; 1.1433x over previous
//
#include <hip/hip_runtime.h>

typedef unsigned short ushort_t;
typedef unsigned int uint_t;
typedef __attribute__((ext_vector_type(8))) short short8;
typedef __attribute__((ext_vector_type(4))) float f32x4;

#define B   128
#define Nv  256
#define Mn  12
#define Hd  128
#define Dd  3
#define Kk  2
#define AFd 82
#define BFd 6
#define BN  (B*Nv)   // 32768

enum { EPI_NONE = 0, EPI_LRELU = 1 };

__device__ __forceinline__ float lrelu(float x) { return x > 0.f ? x : 0.1f * x; }
__device__ __forceinline__ float sigmoidf(float x) { return 1.f / (1.f + expf(-x)); }
__device__ __forceinline__ ushort_t f2b(float x) {
    uint_t u = __float_as_uint(x);
    return (ushort_t)((u + 0x7FFFu + ((u >> 16) & 1u)) >> 16);
}
__device__ __forceinline__ float b2f(ushort_t s) {
    return __uint_as_float(((uint_t)s) << 16);
}
__device__ __forceinline__ void b2f4(uint2 u, float* o) {
    o[0] = __uint_as_float((u.x & 0xFFFFu) << 16);
    o[1] = __uint_as_float(u.x & 0xFFFF0000u);
    o[2] = __uint_as_float((u.y & 0xFFFFu) << 16);
    o[3] = __uint_as_float(u.y & 0xFFFF0000u);
}

// ---------------- fused weight prep (one launch) ----------------
struct PrepJob {
    const float* W;
    long sliceStride;
    int K, ldw, nPerSlice, Kspan, KpadRow, kDst, total, outOff, blockStart;
};
struct PrepJobs { PrepJob j[18]; int nJobs; };

__global__ __launch_bounds__(256) void k_prep_all(PrepJobs P, ushort_t* __restrict__ WT)
{
    int bid = blockIdx.x;
    int ji = 0;
    #pragma unroll 1
    while (ji + 1 < P.nJobs && P.j[ji + 1].blockStart <= bid) ++ji;
    const PrepJob J = P.j[ji];
    const int idx = (bid - J.blockStart) * 256 + threadIdx.x;
    if (idx >= J.total) return;
    const int n = idx / J.Kspan, k = idx % J.Kspan;
    const int slice = n / J.nPerSlice, nn = n % J.nPerSlice;
    float v = (k < J.K) ? J.W[(size_t)slice * J.sliceStride + (size_t)k * J.ldw + nn] : 0.f;
    WT[(size_t)J.outOff + (size_t)n * J.KpadRow + J.kDst + k] = f2b(v);
}

// qtab[d][j][h] (bf16) = sum_f init_bond[j,f] * U2_w[d][128+f][h]
__global__ __launch_bounds__(256) void k_qtab(const float* __restrict__ init_bond,
                                              const float* __restrict__ U2w,
                                              ushort_t* __restrict__ qt)
{
    const int d = blockIdx.x;
    const float* W = U2w + (size_t)d * (Hd + BFd) * Hd + (size_t)Hd * Hd;
    ushort_t* q = qt + (size_t)d * 12 * Hd;
    for (int idx = threadIdx.x; idx < 12 * Hd; idx += 256) {
        const int j = idx >> 7, h = idx & 127;
        float s = 0.f;
        #pragma unroll
        for (int f = 0; f < BFd; ++f) s += init_bond[j * BFd + f] * W[f * Hd + h];
        q[idx] = f2b(s);
    }
}

// ---------------- embed GEMM (fp32 gathered A, 64x128 tile) ----------------
template<int EPI, bool ABF, bool OBF>
__global__ __launch_bounds__(256) void mgemm(
    const void* __restrict__ A1v, int lda1, int K1,
    const int* __restrict__ rowidx,
    const ushort_t* __restrict__ Wt, int Kpad,
    const float* __restrict__ b1,
    void* __restrict__ outv, long ldo)
{
    const int t    = threadIdx.x;
    const int lane = t & 63;
    const int w    = t >> 6;
    const int wm   = w >> 1, wn = w & 1;
    const int lr   = lane & 15, lg = lane >> 4;
    const int row0 = blockIdx.x * 64;

    __shared__ ushort_t As[64 * 64];
    __shared__ ushort_t Bs[128 * 64];

    f32x4 acc[2][4];
    #pragma unroll
    for (int i = 0; i < 2; ++i)
        #pragma unroll
        for (int j = 0; j < 4; ++j)
            acc[i][j] = (f32x4){0.f, 0.f, 0.f, 0.f};

    const int r_st = t >> 2, q4 = t & 3;
    const int c_st = t >> 1, half = t & 1;
    const int grow = row0 + r_st;
    const long arow = rowidx ? (long)rowidx[grow] : (long)grow;

    const int nck = Kpad >> 6;
    for (int ck = 0; ck < nck; ++ck) {
        if (ck) __syncthreads();
        {
            const int kb = ck * 64 + q4 * 16;
            union { ushort_t us[16]; uint4 qv[2]; } tmp;
            #pragma unroll
            for (int j = 0; j < 16; ++j) {
                const int kg = kb + j;
                ushort_t v = 0;
                if (kg < K1) {
                    if (ABF) v = ((const ushort_t*)A1v)[(size_t)arow * lda1 + kg];
                    else     v = f2b(((const float*)A1v)[(size_t)arow * lda1 + kg]);
                }
                tmp.us[j] = v;
            }
            #pragma unroll
            for (int j = 0; j < 2; ++j) {
                int byte = r_st * 128 + q4 * 32 + j * 16;
                byte ^= ((r_st & 7) << 4);
                *(uint4*)((char*)As + byte) = tmp.qv[j];
            }
        }
        {
            const ushort_t* src = Wt + (size_t)c_st * Kpad + ck * 64 + half * 32;
            #pragma unroll
            for (int v2 = 0; v2 < 4; ++v2) {
                uint4 wv = ((const uint4*)src)[v2];
                int byte = c_st * 128 + half * 64 + v2 * 16;
                byte ^= ((c_st & 7) << 4);
                *(uint4*)((char*)Bs + byte) = wv;
            }
        }
        __syncthreads();
        #pragma unroll
        for (int ks = 0; ks < 64; ks += 32) {
            short8 af[2], bfr[4];
            #pragma unroll
            for (int mf = 0; mf < 2; ++mf) {
                const int row = wm * 32 + mf * 16 + lr;
                int byte = row * 128 + (ks + lg * 8) * 2;
                byte ^= ((row & 7) << 4);
                af[mf] = *(const short8*)((const char*)As + byte);
            }
            #pragma unroll
            for (int nf = 0; nf < 4; ++nf) {
                const int col = wn * 64 + nf * 16 + lr;
                int byte = col * 128 + (ks + lg * 8) * 2;
                byte ^= ((col & 7) << 4);
                bfr[nf] = *(const short8*)((const char*)Bs + byte);
            }
            #pragma unroll
            for (int mf = 0; mf < 2; ++mf)
                #pragma unroll
                for (int nf = 0; nf < 4; ++nf)
                    acc[mf][nf] = __builtin_amdgcn_mfma_f32_16x16x32_bf16(
                        af[mf], bfr[nf], acc[mf][nf], 0, 0, 0);
        }
    }

    #pragma unroll
    for (int mf = 0; mf < 2; ++mf) {
        #pragma unroll
        for (int nf = 0; nf < 4; ++nf) {
            const int c = wn * 64 + nf * 16 + lr;
            #pragma unroll
            for (int reg = 0; reg < 4; ++reg) {
                const int r = wm * 32 + mf * 16 + lg * 4 + reg;
                const size_t row = (size_t)row0 + r;
                float v = acc[mf][nf][reg];
                if (b1) v += b1[c];
                if constexpr (EPI == EPI_LRELU) v = lrelu(v);
                const size_t oidx = row * ldo + c;
                if (OBF) ((ushort_t*)outv)[oidx] = f2b(v);
                else     ((float*)outv)[oidx] = v;
            }
        }
    }
}

// ---------------- fused attention-score + P projection ----------------
// grid (BN/64, 3): ky 0,1 -> a[b,ky,n] tanh-dot ; ky 2 -> P = vf@U2v + b
__global__ __launch_bounds__(256) void k_tdp(
    const ushort_t* __restrict__ vfb,
    const ushort_t* __restrict__ Wt,      // [wa 256 cols | u2v 128 cols], Kpad 128
    const float* __restrict__ waB,        // 2*128
    const float* __restrict__ u2B,        // 128
    const float* __restrict__ sf,         // [B][128]
    const float* __restrict__ wbmmW,      // 2*128
    const float* __restrict__ wbmmB,      // 2
    float* __restrict__ a_out,            // [B][2][256]
    ushort_t* __restrict__ Pout)
{
    const int t = threadIdx.x;
    const int lane = t & 63, w = t >> 6;
    const int wm = w >> 1, wn = w & 1;
    const int lr = lane & 15, lg = lane >> 4;
    const int row0 = blockIdx.x * 64;
    const int ky = blockIdx.y;
    const int b = row0 >> 8;

    __shared__ ushort_t As[64 * 128];
    __shared__ ushort_t Bs[128 * 64];
    __shared__ float EUs[128], EBb[128];
    __shared__ float red[64][2];

    {
        const int r_st = t >> 2, q4 = t & 3;
        const ushort_t* src = vfb + (size_t)(row0 + r_st) * Hd + q4 * 32;
        #pragma unroll
        for (int j = 0; j < 4; ++j) {
            uint4 v = ((const uint4*)src)[j];
            int byte = r_st * 256 + q4 * 64 + j * 16;
            byte ^= ((r_st & 7) << 4);
            *(uint4*)((char*)As + byte) = v;
        }
    }
    const ushort_t* Wty = Wt + (size_t)ky * 16384;
    const int c_st = t >> 1, half = t & 1;

    f32x4 acc[2][4];
    #pragma unroll
    for (int i = 0; i < 2; ++i)
        #pragma unroll
        for (int j = 0; j < 4; ++j)
            acc[i][j] = (f32x4){0.f, 0.f, 0.f, 0.f};

    #pragma unroll
    for (int ck = 0; ck < 2; ++ck) {
        if (ck) __syncthreads();
        {
            const ushort_t* src = Wty + (size_t)c_st * 128 + ck * 64 + half * 32;
            #pragma unroll
            for (int v2 = 0; v2 < 4; ++v2) {
                uint4 wv = ((const uint4*)src)[v2];
                int byte = c_st * 128 + half * 64 + v2 * 16;
                byte ^= ((c_st & 7) << 4);
                *(uint4*)((char*)Bs + byte) = wv;
            }
        }
        __syncthreads();
        #pragma unroll
        for (int ks = 0; ks < 64; ks += 32) {
            short8 af[2], bfr[4];
            #pragma unroll
            for (int mf = 0; mf < 2; ++mf) {
                const int row = wm * 32 + mf * 16 + lr;
                int byte = row * 256 + (ck * 64 + ks + lg * 8) * 2;
                byte ^= ((row & 7) << 4);
                af[mf] = *(const short8*)((const char*)As + byte);
            }
            #pragma unroll
            for (int nf = 0; nf < 4; ++nf) {
                const int col = wn * 64 + nf * 16 + lr;
                int byte = col * 128 + (ks + lg * 8) * 2;
                byte ^= ((col & 7) << 4);
                bfr[nf] = *(const short8*)((const char*)Bs + byte);
            }
            #pragma unroll
            for (int mf = 0; mf < 2; ++mf)
                #pragma unroll
                for (int nf = 0; nf < 4; ++nf)
                    acc[mf][nf] = __builtin_amdgcn_mfma_f32_16x16x32_bf16(
                        af[mf], bfr[nf], acc[mf][nf], 0, 0, 0);
        }
    }

    if (ky == 2) {
        #pragma unroll
        for (int mf = 0; mf < 2; ++mf)
            #pragma unroll
            for (int nf = 0; nf < 4; ++nf) {
                const int c = wn * 64 + nf * 16 + lr;
                #pragma unroll
                for (int reg = 0; reg < 4; ++reg) {
                    const int r = wm * 32 + mf * 16 + lg * 4 + reg;
                    Pout[(size_t)(row0 + r) * Hd + c] = f2b(acc[mf][nf][reg] + u2B[c]);
                }
            }
    } else {
        __syncthreads();
        if (t < 128) {
            EUs[t] = sf[b * Hd + t] * wbmmW[ky * Hd + t];
            EBb[t] = waB[ky * Hd + t];
        }
        __syncthreads();
        #pragma unroll
        for (int mf = 0; mf < 2; ++mf) {
            #pragma unroll
            for (int reg = 0; reg < 4; ++reg) {
                float p = 0.f;
                #pragma unroll
                for (int nf = 0; nf < 4; ++nf) {
                    const int c = wn * 64 + nf * 16 + lr;
                    p += tanhf(acc[mf][nf][reg] + EBb[c]) * EUs[c];
                }
                p += __shfl_xor(p, 1); p += __shfl_xor(p, 2);
                p += __shfl_xor(p, 4); p += __shfl_xor(p, 8);
                if (lr == 0) red[wm * 32 + mf * 16 + lg * 4 + reg][wn] = p;
            }
        }
        __syncthreads();
        if (t < 64) {
            const int gr = row0 + t;
            a_out[(size_t)(gr >> 8) * 512 + (size_t)ky * 256 + (gr & 255)] =
                red[t][0] + red[t][1] + wbmmB[ky];
        }
    }
}

// ---------------- MEGA: gather+U1 -> ZMAIN -> GRU(main), all in one block ----
__global__ __launch_bounds__(256) void k_mega(
    const ushort_t* __restrict__ vfb,
    const ushort_t* __restrict__ Pb,
    const ushort_t* __restrict__ qt,
    const int* __restrict__ aadj, const int* __restrict__ badj,
    const int* __restrict__ edge, const float* __restrict__ nmask,
    const ushort_t* __restrict__ wt_u1,    // 128 cols, Kpad 256
    const ushort_t* __restrict__ wt_zm1,   // 128 cols, Kpad 128
    const ushort_t* __restrict__ wt_rz,    // 256 cols, Kpad 256 (k<128 wih, k>=128 whh)
    const ushort_t* __restrict__ wt_inn,   // 128 cols, Kpad 128
    const ushort_t* __restrict__ wt_hn,    // 128 cols, Kpad 128
    const float* __restrict__ u1b,
    const float* __restrict__ zm1b,
    const float* __restrict__ bih, const float* __restrict__ bhh,
    const float* __restrict__ czm2, const float* __restrict__ s2m,
    void* __restrict__ outv, const int finalFp32)
{
    const int t = threadIdx.x;
    const int lane = t & 63, w = t >> 6;
    const int wm = w >> 1, wn = w & 1;
    const int lr = lane & 15, lg = lane >> 4;
    const int row0 = blockIdx.x * 64;
    const int b = row0 >> 8;

    __shared__ ushort_t As[64 * 256];      // [row][k] swizzled: [VF | NEI->MS->HID]
    __shared__ ushort_t Bs[128 * 64];
    __shared__ int      aiS[64 * Mn];
    __shared__ ushort_t eiS[64 * Mn];
    __shared__ float    mkS[64 * Mn];

    // ---- adjacency ----
    for (int i = t; i < 64 * Mn; i += 256) {
        const int r = i / Mn, m = i - r * Mn;
        const long g = (long)(row0 + r) * Mn + m;
        aiS[i] = aadj[g];
        eiS[i] = (ushort_t)edge[badj[g]];
        mkS[i] = nmask[g];
    }
    // ---- VF rows -> As cols 0..127 ----
    {
        const int r_st = t >> 2, q4 = t & 3;
        const ushort_t* src = vfb + (size_t)(row0 + r_st) * Hd + q4 * 32;
        #pragma unroll
        for (int j = 0; j < 4; ++j) {
            uint4 v = ((const uint4*)src)[j];
            int byte = r_st * 512 + q4 * 64 + j * 16;
            byte ^= ((r_st & 7) << 4);
            *(uint4*)((char*)As + byte) = v;
        }
    }
    __syncthreads();
    // ---- NEI gather -> As cols 128..255 ----
    #pragma unroll 1
    for (int it = 0; it < 4; ++it) {
        const int idx = it * 256 + t;
        const int r = idx >> 4, h0 = (idx & 15) * 8;
        float a8[8] = {0.f,0.f,0.f,0.f,0.f,0.f,0.f,0.f};
        #pragma unroll
        for (int m = 0; m < Mn; ++m) {
            const int ai = aiS[r * Mn + m];
            const float mk = mkS[r * Mn + m];
            const uint4 pv = *(const uint4*)&Pb[(size_t)ai * Hd + h0];
            const uint4 qv = *(const uint4*)&qt[(size_t)eiS[r * Mn + m] * Hd + h0];
            const ushort_t* pp = (const ushort_t*)&pv;
            const ushort_t* qq = (const ushort_t*)&qv;
            #pragma unroll
            for (int e = 0; e < 8; ++e) {
                const float v = b2f(pp[e]) + b2f(qq[e]);
                a8[e] = fmaf(mk, lrelu(v), a8[e]);
            }
        }
        ushort_t o8[8];
        #pragma unroll
        for (int e = 0; e < 8; ++e) o8[e] = f2b(a8[e]);
        int byte = r * 512 + (128 + h0) * 2;
        byte ^= ((r & 7) << 4);
        *(uint4*)((char*)As + byte) = *(const uint4*)o8;
    }
    __syncthreads();

    const int c_st = t >> 1, half = t & 1;
    f32x4 acc[2][4];

    // GEMM pass macro: stage Bs chunk, MFMA over A at col offset
#define ZERO_ACC() { _Pragma("unroll") for (int i = 0; i < 2; ++i) _Pragma("unroll") for (int j = 0; j < 4; ++j) acc[i][j] = (f32x4){0.f,0.f,0.f,0.f}; }
#define GEMM_CHUNK(WBASE, KPADW, CK, AOFF) { \
        const ushort_t* src = (WBASE) + (size_t)c_st * (KPADW) + (CK) * 64 + half * 32; \
        _Pragma("unroll") \
        for (int v2 = 0; v2 < 4; ++v2) { \
            uint4 wv = ((const uint4*)src)[v2]; \
            int byte = c_st * 128 + half * 64 + v2 * 16; \
            byte ^= ((c_st & 7) << 4); \
            *(uint4*)((char*)Bs + byte) = wv; \
        } \
        __syncthreads(); \
        _Pragma("unroll") \
        for (int ks = 0; ks < 64; ks += 32) { \
            short8 af[2], bfr[4]; \
            _Pragma("unroll") \
            for (int mf = 0; mf < 2; ++mf) { \
                const int row = wm * 32 + mf * 16 + lr; \
                int byte = row * 512 + ((AOFF) + ks + lg * 8) * 2; \
                byte ^= ((row & 7) << 4); \
                af[mf] = *(const short8*)((const char*)As + byte); \
            } \
            _Pragma("unroll") \
            for (int nf = 0; nf < 4; ++nf) { \
                const int col = wn * 64 + nf * 16 + lr; \
                int byte = col * 128 + (ks + lg * 8) * 2; \
                byte ^= ((col & 7) << 4); \
                bfr[nf] = *(const short8*)((const char*)Bs + byte); \
            } \
            _Pragma("unroll") \
            for (int mf = 0; mf < 2; ++mf) \
                _Pragma("unroll") \
                for (int nf = 0; nf < 4; ++nf) \
                    acc[mf][nf] = __builtin_amdgcn_mfma_f32_16x16x32_bf16(af[mf], bfr[nf], acc[mf][nf], 0, 0, 0); \
        } \
        __syncthreads(); }

    // ---- U1: MS = lrelu([VF|NEI]@Wu1 + b) ----
    ZERO_ACC();
    #pragma unroll 1
    for (int ck = 0; ck < 4; ++ck) GEMM_CHUNK(wt_u1, 256, ck, ck * 64);
    float msv[2][4][4];
    #pragma unroll
    for (int mf = 0; mf < 2; ++mf)
        #pragma unroll
        for (int nf = 0; nf < 4; ++nf) {
            const int c = wn * 64 + nf * 16 + lr;
            const float bb = u1b[c];
            #pragma unroll
            for (int reg = 0; reg < 4; ++reg)
                msv[mf][nf][reg] = lrelu(acc[mf][nf][reg] + bb);
        }
    // write MS over NEI region
    #pragma unroll
    for (int mf = 0; mf < 2; ++mf)
        #pragma unroll
        for (int nf = 0; nf < 4; ++nf) {
            const int c = wn * 64 + nf * 16 + lr;
            #pragma unroll
            for (int reg = 0; reg < 4; ++reg) {
                const int row = wm * 32 + mf * 16 + lg * 4 + reg;
                int byte = row * 512 + (128 + c) * 2;
                byte ^= ((row & 7) << 4);
                *(ushort_t*)((char*)As + byte) = f2b(msv[mf][nf][reg]);
            }
        }
    __syncthreads();

    // ---- ZMAIN: HID = (1-z)*MS + z*s2m, z = sig(MS@Wzm1 + b + czm2) ----
    ZERO_ACC();
    #pragma unroll 1
    for (int ck = 0; ck < 2; ++ck) GEMM_CHUNK(wt_zm1, 128, ck, 128 + ck * 64);
    #pragma unroll
    for (int mf = 0; mf < 2; ++mf)
        #pragma unroll
        for (int nf = 0; nf < 4; ++nf) {
            const int c = wn * 64 + nf * 16 + lr;
            const float bb = zm1b[c] + czm2[b * Hd + c];
            const float s2 = s2m[b * Hd + c];
            #pragma unroll
            for (int reg = 0; reg < 4; ++reg) {
                const float z = sigmoidf(acc[mf][nf][reg] + bb);
                const float hid = (1.f - z) * msv[mf][nf][reg] + z * s2;
                const int row = wm * 32 + mf * 16 + lg * 4 + reg;
                int byte = row * 512 + (128 + c) * 2;
                byte ^= ((row & 7) << 4);
                *(ushort_t*)((char*)As + byte) = f2b(hid);   // HID over MS
            }
        }
    __syncthreads();

    // ---- GRU gates ----
    float rv[2][4][4], zv[2][4][4], innv[2][4][4];
    // r: K=256 [HID|VF]
    ZERO_ACC();
    #pragma unroll 1
    for (int ck = 0; ck < 4; ++ck) GEMM_CHUNK(wt_rz, 256, ck, (ck < 2) ? (128 + ck * 64) : ((ck - 2) * 64));
    #pragma unroll
    for (int mf = 0; mf < 2; ++mf)
        #pragma unroll
        for (int nf = 0; nf < 4; ++nf) {
            const int c = wn * 64 + nf * 16 + lr;
            const float bb = bih[c] + bhh[c];
            #pragma unroll
            for (int reg = 0; reg < 4; ++reg)
                rv[mf][nf][reg] = sigmoidf(acc[mf][nf][reg] + bb);
        }
    // z: K=256 [HID|VF], cols 128..255 of wt_rz
    ZERO_ACC();
    #pragma unroll 1
    for (int ck = 0; ck < 4; ++ck) GEMM_CHUNK(wt_rz + 128 * 256, 256, ck, (ck < 2) ? (128 + ck * 64) : ((ck - 2) * 64));
    #pragma unroll
    for (int mf = 0; mf < 2; ++mf)
        #pragma unroll
        for (int nf = 0; nf < 4; ++nf) {
            const int c = wn * 64 + nf * 16 + lr;
            const float bb = bih[128 + c] + bhh[128 + c];
            #pragma unroll
            for (int reg = 0; reg < 4; ++reg)
                zv[mf][nf][reg] = sigmoidf(acc[mf][nf][reg] + bb);
        }
    // inn: K=128 HID
    ZERO_ACC();
    #pragma unroll 1
    for (int ck = 0; ck < 2; ++ck) GEMM_CHUNK(wt_inn, 128, ck, 128 + ck * 64);
    #pragma unroll
    for (int mf = 0; mf < 2; ++mf)
        #pragma unroll
        for (int nf = 0; nf < 4; ++nf) {
            const int c = wn * 64 + nf * 16 + lr;
            const float bb = bih[256 + c];
            #pragma unroll
            for (int reg = 0; reg < 4; ++reg)
                innv[mf][nf][reg] = acc[mf][nf][reg] + bb;
        }
    // hn: K=128 VF
    ZERO_ACC();
    #pragma unroll 1
    for (int ck = 0; ck < 2; ++ck) GEMM_CHUNK(wt_hn, 128, ck, ck * 64);

    // ---- combine + store ----
    #pragma unroll
    for (int mf = 0; mf < 2; ++mf)
        #pragma unroll
        for (int nf = 0; nf < 4; ++nf) {
            const int c = wn * 64 + nf * 16 + lr;
            const float bb = bhh[256 + c];
            #pragma unroll
            for (int reg = 0; reg < 4; ++reg) {
                const int rl = wm * 32 + mf * 16 + lg * 4 + reg;
                const float hn = acc[mf][nf][reg] + bb;
                const float n = tanhf(innv[mf][nf][reg] + rv[mf][nf][reg] * hn);
                int byte = rl * 512 + c * 2;
                byte ^= ((rl & 7) << 4);
                const float h = b2f(*(const ushort_t*)((const char*)As + byte));
                const float z = zv[mf][nf][reg];
                const float o = (1.f - z) * n + z * h;
                const size_t oidx = (size_t)(row0 + rl) * Hd + c;
                if (finalFp32) ((float*)outv)[oidx] = o;
                else           ((ushort_t*)outv)[oidx] = f2b(o);
            }
        }
#undef GEMM_CHUNK
#undef ZERO_ACC
}

// ---------------- GEMV building block (fp32 weights) ----------------
__device__ __forceinline__ void gemv128(const float* __restrict__ W, int ldw, int off,
                                        const float* __restrict__ x, int K,
                                        float (*red)[32][4], float* __restrict__ y, int t)
{
    const int gq = t & 31, hs = t >> 5;
    const int hn = K >> 3;
    f32x4 acc = (f32x4){0.f, 0.f, 0.f, 0.f};
    const float* Wp = W + (size_t)off + (size_t)gq * 4;
    const int h0 = hs * hn;
    #pragma unroll 8
    for (int i = 0; i < hn; ++i) {
        const float4 wv = *(const float4*)&Wp[(size_t)(h0 + i) * ldw];
        const float xv = x[h0 + i];
        acc.x = fmaf(xv, wv.x, acc.x);
        acc.y = fmaf(xv, wv.y, acc.y);
        acc.z = fmaf(xv, wv.z, acc.z);
        acc.w = fmaf(xv, wv.w, acc.w);
    }
    *(f32x4*)&red[hs][gq][0] = acc;
    __syncthreads();
    if (t < 128) {
        float s = 0.f;
        #pragma unroll
        for (int p = 0; p < 8; ++p) s += red[p][t >> 2][t & 3];
        y[t] = s;
    }
    __syncthreads();
}

// ---------------- fused softmax + supernode chain, one block per b ----------------
__global__ __launch_bounds__(256) void k_super(
    const float* __restrict__ a_buf, const float* __restrict__ vmask,
    const ushort_t* __restrict__ vfb,
    const float* __restrict__ sf_in,
    const float* __restrict__ Wm, const float* __restrict__ bm,
    const float* __restrict__ Wm2s, const float* __restrict__ bm2s,
    const float* __restrict__ Ws2m, const float* __restrict__ bs2m,
    const float* __restrict__ Wsup, const float* __restrict__ bsup,
    const float* __restrict__ Wzm2, const float* __restrict__ bzm2,
    const float* __restrict__ Wzs1, const float* __restrict__ bzs1,
    const float* __restrict__ Wzs2, const float* __restrict__ bzs2,
    const float* __restrict__ gwih, const float* __restrict__ gwhh,
    const float* __restrict__ gbih, const float* __restrict__ gbhh,
    float* __restrict__ s2m_g, float* __restrict__ czm2_g,
    float* __restrict__ sf_out)
{
    const int b = blockIdx.x, t = threadIdx.x;
    const int wid = t >> 6, lane = t & 63;
    __shared__ float red[8][32][4];
    __shared__ float att0[256], att1[256];
    __shared__ float sfl[128], tbA[128], tbB[128], mv[256];
    __shared__ float ms2[128], s2ml[128], ssl[128], hsl[128], tmp1[128], tmp2[128];
    __shared__ float gib[384], ghb[384];
    __shared__ float saS[2];
    __shared__ float lm[4][2], ls[4][2];

    const float v0 = a_buf[(size_t)b * 512 + t];
    const float v1 = a_buf[(size_t)b * 512 + 256 + t];
    const float vm = vmask[b * Nv + t];
    float m0 = v0, m1 = v1;
    #pragma unroll
    for (int o = 1; o < 64; o <<= 1) {
        m0 = fmaxf(m0, __shfl_xor(m0, o));
        m1 = fmaxf(m1, __shfl_xor(m1, o));
    }
    if (lane == 0) { lm[wid][0] = m0; lm[wid][1] = m1; }
    __syncthreads();
    m0 = fmaxf(fmaxf(lm[0][0], lm[1][0]), fmaxf(lm[2][0], lm[3][0]));
    m1 = fmaxf(fmaxf(lm[0][1], lm[1][1]), fmaxf(lm[2][1], lm[3][1]));
    const float e0v = expf(v0 - m0) * vm;
    const float e1v = expf(v1 - m1) * vm;
    float s0 = e0v, s1 = e1v;
    #pragma unroll
    for (int o = 1; o < 64; o <<= 1) {
        s0 += __shfl_xor(s0, o);
        s1 += __shfl_xor(s1, o);
    }
    if (lane == 0) { ls[wid][0] = s0; ls[wid][1] = s1; }
    if (t < 128) sfl[t] = sf_in[b * Hd + t];
    __syncthreads();
    s0 = ls[0][0] + ls[1][0] + ls[2][0] + ls[3][0];
    s1 = ls[0][1] + ls[1][1] + ls[2][1] + ls[3][1];
    att0[t] = e0v / (s0 + 1e-6f);
    att1[t] = e1v / (s1 + 1e-6f);
    if (t == 0) { saS[0] = s0 / (s0 + 1e-6f); saS[1] = s1 / (s1 + 1e-6f); }
    __syncthreads();

    {
        const int hq = t & 31, ns = t >> 5;
        f32x4 a0 = (f32x4){0.f,0.f,0.f,0.f}, a1 = (f32x4){0.f,0.f,0.f,0.f};
        const ushort_t* base = vfb + (size_t)b * Nv * Hd + hq * 4;
        #pragma unroll 8
        for (int i = 0; i < 32; ++i) {
            const int n = ns * 32 + i;
            float xv[4];
            b2f4(*(const uint2*)&base[(size_t)n * Hd], xv);
            const float w0 = att0[n], w1 = att1[n];
            a0.x = fmaf(w0, xv[0], a0.x); a0.y = fmaf(w0, xv[1], a0.y);
            a0.z = fmaf(w0, xv[2], a0.z); a0.w = fmaf(w0, xv[3], a0.w);
            a1.x = fmaf(w1, xv[0], a1.x); a1.y = fmaf(w1, xv[1], a1.y);
            a1.z = fmaf(w1, xv[2], a1.z); a1.w = fmaf(w1, xv[3], a1.w);
        }
        *(f32x4*)&red[ns][hq][0] = a0;
        __syncthreads();
        if (t < 128) { float s = 0.f;
            #pragma unroll
            for (int p = 0; p < 8; ++p) s += red[p][t >> 2][t & 3];
            tbA[t] = s; }
        __syncthreads();
        *(f32x4*)&red[ns][hq][0] = a1;
        __syncthreads();
        if (t < 128) { float s = 0.f;
            #pragma unroll
            for (int p = 0; p < 8; ++p) s += red[p][t >> 2][t & 3];
            tbB[t] = s; }
        __syncthreads();
    }

    gemv128(Wm, Hd, 0, tbA, Hd, red, mv, t);
    gemv128(Wm + Hd * Hd, Hd, 0, tbB, Hd, red, mv + 128, t);
    mv[t] += saS[t >> 7] * bm[t];
    __syncthreads();

    gemv128(Wm2s, Hd, 0, mv, 2 * Hd, red, tmp1, t);
    if (t < 128) ms2[t] = tanhf(tmp1[t] + bm2s[t]);
    __syncthreads();

    gemv128(Ws2m, Hd, 0, sfl, Hd, red, tmp1, t);
    if (t < 128) { const float v = tanhf(tmp1[t] + bs2m[t]); s2ml[t] = v; s2m_g[b * Hd + t] = v; }
    __syncthreads();
    gemv128(Wsup, Hd, 0, sfl, Hd, red, tmp1, t);
    if (t < 128) ssl[t] = tanhf(tmp1[t] + bsup[t]);
    __syncthreads();

    gemv128(Wzm2, Hd, 0, s2ml, Hd, red, tmp1, t);
    if (t < 128) czm2_g[b * Hd + t] = tmp1[t] + bzm2[t];

    gemv128(Wzs1, Hd, 0, ssl, Hd, red, tmp1, t);
    gemv128(Wzs2, Hd, 0, ms2, Hd, red, tmp2, t);
    if (t < 128) {
        const float zs = sigmoidf(tmp1[t] + bzs1[t] + tmp2[t] + bzs2[t]);
        hsl[t] = (1.f - zs) * ssl[t] + zs * ms2[t];
    }
    __syncthreads();

    #pragma unroll 1
    for (int c = 0; c < 3; ++c) {
        gemv128(gwih, 3 * Hd, c * Hd, hsl, Hd, red, tmp1, t);
        if (t < 128) gib[c * Hd + t] = tmp1[t] + gbih[c * Hd + t];
        gemv128(gwhh, 3 * Hd, c * Hd, sfl, Hd, red, tmp2, t);
        if (t < 128) ghb[c * Hd + t] = tmp2[t] + gbhh[c * Hd + t];
    }
    __syncthreads();
    if (t < 128) {
        const float r = sigmoidf(gib[t] + ghb[t]);
        const float z = sigmoidf(gib[128 + t] + ghb[128 + t]);
        const float n = tanhf(gib[256 + t] + r * ghb[256 + t]);
        sf_out[b * Hd + t] = (1.f - z) * n + z * sfl[t];
    }
}

// sf[b,h] = sum_n vf[b,n,h]*vmask[b,n]  (bf16 vf)
__global__ __launch_bounds__(256) void k_sfv(const ushort_t* __restrict__ vfb,
                                             const float* __restrict__ vmask,
                                             float* __restrict__ sf)
{
    const int b = blockIdx.x, t = threadIdx.x;
    __shared__ float vm[256];
    __shared__ float red[8][32][4];
    vm[t] = vmask[b * Nv + t];
    __syncthreads();
    const int hq = t & 31, ns = t >> 5;
    f32x4 acc = (f32x4){0.f,0.f,0.f,0.f};
    const ushort_t* base = vfb + (size_t)b * Nv * Hd + hq * 4;
    #pragma unroll 8
    for (int i = 0; i < 32; ++i) {
        const int n = ns * 32 + i;
        float xv[4];
        b2f4(*(const uint2*)&base[(size_t)n * Hd], xv);
        const float w = vm[n];
        acc.x = fmaf(w, xv[0], acc.x); acc.y = fmaf(w, xv[1], acc.y);
        acc.z = fmaf(w, xv[2], acc.z); acc.w = fmaf(w, xv[3], acc.w);
    }
    *(f32x4*)&red[ns][hq][0] = acc;
    __syncthreads();
    if (t < 128) {
        float s = 0.f;
        #pragma unroll
        for (int p = 0; p < 8; ++p) s += red[p][t >> 2][t & 3];
        sf[b * Hd + t] = s;
    }
}

__global__ __launch_bounds__(256) void k_copy(const float* __restrict__ src,
                                              float* __restrict__ dst, int n)
{
    const int i = blockIdx.x * 256 + threadIdx.x;
    if (i < n) dst[i] = src[i];
}

extern "C" void kernel_launch(void* const* d_in, const int* in_sizes, int n_in,
                              void* d_out, int out_size, void* d_ws, size_t ws_size,
                              hipStream_t stream)
{
    (void)in_sizes; (void)n_in; (void)out_size;

    const float* vertex_mask = (const float*)d_in[1];
    const int*   vertex      = (const int*)d_in[2];
    const int*   edge        = (const int*)d_in[3];
    const int*   atom_adj    = (const int*)d_in[4];
    const int*   bond_adj    = (const int*)d_in[5];
    const float* nbs_mask    = (const float*)d_in[6];
    const float* init_atom   = (const float*)d_in[7];
    const float* init_bond   = (const float*)d_in[8];
    const float* emb_w  = (const float*)d_in[9];
    const float* emb_b  = (const float*)d_in[10];
    const float* Wa_w   = (const float*)d_in[11];
    const float* Wa_b   = (const float*)d_in[12];
    const float* Wbmm_w = (const float*)d_in[13];
    const float* Wbmm_b = (const float*)d_in[14];
    const float* Wm_w   = (const float*)d_in[15];
    const float* Wm_b   = (const float*)d_in[16];
    const float* Wm2s_w = (const float*)d_in[17];
    const float* Wm2s_b = (const float*)d_in[18];
    const float* Ws2m_w = (const float*)d_in[19];
    const float* Ws2m_b = (const float*)d_in[20];
    const float* Wsup_w = (const float*)d_in[21];
    const float* Wsup_b = (const float*)d_in[22];
    const float* Wzm1_w = (const float*)d_in[23];
    const float* Wzm1_b = (const float*)d_in[24];
    const float* Wzm2_w = (const float*)d_in[25];
    const float* Wzm2_b = (const float*)d_in[26];
    const float* Wzs1_w = (const float*)d_in[27];
    const float* Wzs1_b = (const float*)d_in[28];
    const float* Wzs2_w = (const float*)d_in[29];
    const float* Wzs2_b = (const float*)d_in[30];
    const float* U2_w   = (const float*)d_in[31];
    const float* U2_b   = (const float*)d_in[32];
    const float* U1_w   = (const float*)d_in[33];
    const float* U1_b   = (const float*)d_in[34];
    const float* gm_wih = (const float*)d_in[35];
    const float* gm_whh = (const float*)d_in[36];
    const float* gm_bih = (const float*)d_in[37];
    const float* gm_bhh = (const float*)d_in[38];
    const float* gs_wih = (const float*)d_in[39];
    const float* gs_whh = (const float*)d_in[40];
    const float* gs_bih = (const float*)d_in[41];
    const float* gs_bhh = (const float*)d_in[42];

    const size_t MB = 1u << 20;
    if (ws_size < 40 * MB) return;

    char* base = (char*)d_ws;
    ushort_t* VF0 = (ushort_t*)base;               // 8 MB
    ushort_t* VF1 = (ushort_t*)(base + 8 * MB);    // 8 MB
    ushort_t* Pb  = (ushort_t*)(base + 16 * MB);   // 8 MB
    ushort_t* WT  = (ushort_t*)(base + 24 * MB);   // ~0.82 MB
    ushort_t* QT  = (ushort_t*)(base + 26 * MB);   // 3*12*128 bf16
    float*    S   = (float*)(base + 27 * MB);

    float* sfA    = S;
    float* sfB    = S + 16384;
    float* a_buf  = S + 32768;
    float* s2m    = S + 98304;
    float* c_zm2  = S + 114688;

    float* X1 = (float*)d_out;
    float* sf_final = X1 + (size_t)BN * Hd;

    // WT layout (ushort offsets): per layer [wa 256c | u2v 128c | u1 128c(K256) | zm1 128c]
    const int OFF_EMB = 0;
    const int PERD = 98304;
    const int OFF_L0 = 16384;
    const int OFF_RZ = OFF_L0 + 3 * PERD;
    const int OFF_NH = OFF_RZ + 65536;

    PrepJobs PJ;
    int nj = 0, blk0 = 0;
    auto addJob = [&](const float* W, int K, int ldw, long sStride, int nPer,
                      int Kspan, int KpadRow, int kDst, int ncols, int outOff) {
        PrepJob& J = PJ.j[nj++];
        J.W = W; J.K = K; J.ldw = ldw; J.sliceStride = sStride; J.nPerSlice = nPer;
        J.Kspan = Kspan; J.KpadRow = KpadRow; J.kDst = kDst;
        J.total = ncols * Kspan; J.outOff = outOff; J.blockStart = blk0;
        blk0 += (J.total + 255) / 256;
    };
    addJob(emb_w, AFd, Hd, 0, Hd, 128, 128, 0, 128, OFF_EMB);
    for (int d = 0; d < Dd; ++d) {
        const int o = OFF_L0 + d * PERD;
        addJob(Wa_w + (long)d * Kk * Hd * Hd, Hd, Hd, (long)Hd * Hd, Hd, 128, 128, 0, 256, o);
        addJob(U2_w + (long)d * (Hd + BFd) * Hd, Hd, Hd, 0, Hd, 128, 128, 0, 128, o + 32768);
        addJob(U1_w + (long)d * 2 * Hd * Hd, 2 * Hd, Hd, 0, Hd, 256, 256, 0, 128, o + 49152);
        addJob(Wzm1_w + (long)d * Hd * Hd, Hd, Hd, 0, Hd, 128, 128, 0, 128, o + 81920);
    }
    addJob(gm_wih, Hd, 3 * Hd, 0, 256, 128, 256, 0,   256, OFF_RZ);
    addJob(gm_whh, Hd, 3 * Hd, 0, 256, 128, 256, 128, 256, OFF_RZ);
    addJob(gm_wih + 256, Hd, 3 * Hd, 0, 128, 128, 128, 0, 128, OFF_NH);
    addJob(gm_whh + 256, Hd, 3 * Hd, 0, 128, 128, 128, 0, 128, OFF_NH + 16384);
    PJ.nJobs = nj;
    k_prep_all<<<dim3(blk0), dim3(256), 0, stream>>>(PJ, WT);
    k_qtab<<<dim3(Dd), dim3(256), 0, stream>>>(init_bond, U2_w, QT);

    const dim3 blk(256);
    const dim3 g1(BN / 64, 1);

    // embed -> VF0 (bf16)
    mgemm<EPI_LRELU, false, true><<<g1, blk, 0, stream>>>(
        init_atom, AFd, AFd, vertex,
        WT + OFF_EMB, 128, emb_b, VF0, Hd);
    k_sfv<<<dim3(B), blk, 0, stream>>>(VF0, vertex_mask, sfA);

    for (int d = 0; d < Dd; ++d) {
        ushort_t* vin  = (d & 1) ? VF1 : VF0;
        ushort_t* vout = (d & 1) ? VF0 : VF1;
        float* sin  = (d & 1) ? sfB : sfA;
        float* sout = (d & 1) ? sfA : sfB;

        const int o = OFF_L0 + d * PERD;

        // attention scores (ky 0,1) + P projection (ky 2)
        k_tdp<<<dim3(BN / 64, 3), blk, 0, stream>>>(
            vin, WT + o,
            Wa_b + (long)d * Kk * Hd, U2_b + (long)d * Hd,
            sin, Wbmm_w + (long)d * Kk * Hd, Wbmm_b + (long)d * Kk,
            a_buf, Pb);

        // fused softmax + supernode chain
        k_super<<<dim3(B), blk, 0, stream>>>(
            a_buf, vertex_mask, vin, sin,
            Wm_w + (long)d * Kk * Hd * Hd, Wm_b + (long)d * Kk * Hd,
            Wm2s_w + (long)d * Kk * Hd * Hd, Wm2s_b + (long)d * Hd,
            Ws2m_w + (long)d * Hd * Hd, Ws2m_b + (long)d * Hd,
            Wsup_w + (long)d * Hd * Hd, Wsup_b + (long)d * Hd,
            Wzm2_w + (long)d * Hd * Hd, Wzm2_b + (long)d * Hd,
            Wzs1_w + (long)d * Hd * Hd, Wzs1_b + (long)d * Hd,
            Wzs2_w + (long)d * Hd * Hd, Wzs2_b + (long)d * Hd,
            gs_wih, gs_whh, gs_bih, gs_bhh,
            s2m, c_zm2, sout);

        // MEGA: gather+U1 -> ZMAIN -> GRU main -> vf_out
        k_mega<<<g1, blk, 0, stream>>>(
            vin, Pb, QT + (size_t)d * 12 * Hd,
            atom_adj, bond_adj, edge, nbs_mask,
            WT + o + 49152, WT + o + 81920,
            WT + OFF_RZ, WT + OFF_NH, WT + OFF_NH + 16384,
            U1_b + (long)d * Hd, Wzm1_b + (long)d * Hd,
            gm_bih, gm_bhh,
            c_zm2, s2m,
            (d == Dd - 1) ? (void*)X1 : (void*)vout, (d == Dd - 1) ? 1 : 0);
    }

    k_copy<<<dim3((B * Hd + 255) / 256), blk, 0, stream>>>(sfB, sf_final, B * Hd);
}